// Round 5
// baseline (356.903 us; speedup 1.0000x reference)
//
#include <hip/hip_runtime.h>
#include <hip/hip_bf16.h>

// ---------------- problem constants ----------------
#define NB    2
#define NS    1024
#define NPTS  8192
#define NGROUP (NB*NS*4)   // 8192 groups = rows

// ---------------- ws layout (float offsets) ----------------
enum : int {
  OFF_BW2  = 256,      // 8192 bf16: W2 folded, B-frag order
  OFF_W1Q  = 4352,     // 64 x float4 (w0,w1,w2,b) folded L1
  OFF_B2   = 8448,     // 128 f32
  OFF_BW3  = 8576,     // 32768 bf16: W3 folded, B-frag order
  OFF_B3   = 41344,    // 256 f32
  OFF_HB1  = 41600,    // 65536 bf16: combined head L1 (256x256), B-frag order
  OFF_HB1B = 74368,    // 256 f32
  OFF_HB2  = 74624,    // 65536 bf16: combined head L2 (256x256 block-diag)
  OFF_HB2B = 107392,   // 256 f32
  OFF_HB3  = 107648,   // 16384 bf16: combined head L3 (64x256 block-struct)
  OFF_HB3B = 115840,   // 64 f32
  PREP_TOTAL = 189632, // work items in prep
  OFF_FEAT = 146688,            // 8192 * 64 * 3
  OFF_VP   = 1719552,           // 8192 * 256
  OFF_CNT  = 3816704,           // 8192 ints
  OFF_FLAG = 3824896,           // 1 int: 0 = bf16 inputs, 1 = fp32 inputs
};

struct Ptrs { const void* p[25]; };

typedef __attribute__((ext_vector_type(8))) short bf16x8;
typedef __attribute__((ext_vector_type(4))) float f32x4;

template<typename T> struct LD;
template<> struct LD<float> {
  static __device__ __forceinline__ float get(const void* p, int i){ return ((const float*)p)[i]; }
};
template<> struct LD<__hip_bfloat16> {
  static __device__ __forceinline__ float get(const void* p, int i){ return __bfloat162float(((const __hip_bfloat16*)p)[i]); }
};

template<typename T>
__device__ __forceinline__ float bnscale(const void* bn, int C, int c){
  float g = LD<T>::get(bn, c);
  float v = LD<T>::get(bn, 3*C + c);
  return g / sqrtf(v + 1e-5f);
}

__device__ __forceinline__ unsigned short f2bf(float v){
  __hip_bfloat16 hb = __float2bfloat16(v);
  return *reinterpret_cast<unsigned short*>(&hb);
}

// ---------------- kernel -1: detect input dtype ----------------
__global__ __launch_bounds__(256) void detect_kernel(const void* w2, const void* w3, int* flag){
  __shared__ int f;
  int t = threadIdx.x;
  if (t == 0) f = 0;
  __syncthreads();
  int loc = 0;
  const unsigned short* a = (const unsigned short*)w2;
  for (int i = t; i < 8192; i += 256)  loc |= ((a[i] & 0x7F80) == 0x7F80);
  const unsigned short* b = (const unsigned short*)w3;
  for (int i = t; i < 32768; i += 256) loc |= ((b[i] & 0x7F80) == 0x7F80);
  if (loc) atomicOr(&f, 1);
  __syncthreads();
  if (t == 0) flag[0] = f;
}

// ---------------- kernel 0: fold BN; swizzle all GEMM weights to bf16 B-frags ----------------
template<typename T>
__global__ __launch_bounds__(256) void prep_kernel(Ptrs in, float* __restrict__ ws, int want){
  if (((const volatile int*)(ws + OFF_FLAG))[0] != want) return;
  int i = blockIdx.x*256 + threadIdx.x;
  if (i >= PREP_TOTAL) return;
  if (i < 256) { int c = i>>2, d = i&3; float s = bnscale<T>(in.p[4],64,c);
    float v = (d<3) ? LD<T>::get(in.p[3], c*3+d)*s
                    : LD<T>::get(in.p[4],64+c) - LD<T>::get(in.p[4],2*64+c)*s;
    ws[OFF_W1Q+i] = v; return; }
  i -= 256;
  if (i < 8192) { // BW2: 128x64, KT=2
    int j = i&7, f = i>>3, lane = f&63, kn = f>>6, kt = kn&1, nt = kn>>1;
    int n = nt*16 + (lane&15), k = kt*32 + ((lane>>4)<<3) + j;
    float s = bnscale<T>(in.p[6],128,n);
    ((unsigned short*)(ws + OFF_BW2))[i] = f2bf(LD<T>::get(in.p[5], n*64+k)*s); return; }
  i -= 8192;
  if (i < 32768) { // BW3: 256x128, KT=4
    int j = i&7, f = i>>3, lane = f&63, kn = f>>6, kt = kn&3, nt = kn>>2;
    int n = nt*16 + (lane&15), k = kt*32 + ((lane>>4)<<3) + j;
    float s = bnscale<T>(in.p[8],256,n);
    ((unsigned short*)(ws + OFF_BW3))[i] = f2bf(LD<T>::get(in.p[7], n*128+k)*s); return; }
  i -= 32768;
  if (i < 128) { float s = bnscale<T>(in.p[6],128,i);
    ws[OFF_B2+i] = LD<T>::get(in.p[6],128+i) - LD<T>::get(in.p[6],2*128+i)*s; return; }
  i -= 128;
  if (i < 256) { float s = bnscale<T>(in.p[8],256,i);
    ws[OFF_B3+i] = LD<T>::get(in.p[8],256+i) - LD<T>::get(in.p[8],2*256+i)*s; return; }
  i -= 256;
  if (i < 65536) { // HB1: combined 256x256, KT=8
    int j = i&7, f = i>>3, lane = f&63, kn = f>>6, kt = kn&7, nt = kn>>3;
    int n = nt*16 + (lane&15), k = kt*32 + ((lane>>4)<<3) + j;
    float v;
    if (n < 128) v = LD<T>::get(in.p[9],  n*256+k)       * bnscale<T>(in.p[11],128,n);
    else         v = LD<T>::get(in.p[17], (n-128)*256+k) * bnscale<T>(in.p[19],128,n-128);
    ((unsigned short*)(ws + OFF_HB1))[i] = f2bf(v); return; }
  i -= 65536;
  if (i < 256) { int n = i; float v;
    if (n < 128) { float s = bnscale<T>(in.p[11],128,n);
      v = (LD<T>::get(in.p[10],n) - LD<T>::get(in.p[11],2*128+n))*s + LD<T>::get(in.p[11],128+n); }
    else { int m = n-128; float s = bnscale<T>(in.p[19],128,m);
      v = (LD<T>::get(in.p[18],m) - LD<T>::get(in.p[19],2*128+m))*s + LD<T>::get(in.p[19],128+m); }
    ws[OFF_HB1B+n] = v; return; }
  i -= 256;
  if (i < 65536) { // HB2: 256x256 block-diagonal
    int j = i&7, f = i>>3, lane = f&63, kn = f>>6, kt = kn&7, nt = kn>>3;
    int n = nt*16 + (lane&15), k = kt*32 + ((lane>>4)<<3) + j;
    float v = 0.f;
    if (n < 128) { if (k < 128)  v = LD<T>::get(in.p[12], n*128+k)            * bnscale<T>(in.p[14],128,n); }
    else         { if (k >= 128) v = LD<T>::get(in.p[20], (n-128)*128+(k-128)) * bnscale<T>(in.p[22],128,n-128); }
    ((unsigned short*)(ws + OFF_HB2))[i] = f2bf(v); return; }
  i -= 65536;
  if (i < 256) { int n = i; float v;
    if (n < 128) { float s = bnscale<T>(in.p[14],128,n);
      v = (LD<T>::get(in.p[13],n) - LD<T>::get(in.p[14],2*128+n))*s + LD<T>::get(in.p[14],128+n); }
    else { int m = n-128; float s = bnscale<T>(in.p[22],128,m);
      v = (LD<T>::get(in.p[21],m) - LD<T>::get(in.p[22],2*128+m))*s + LD<T>::get(in.p[22],128+m); }
    ws[OFF_HB2B+n] = v; return; }
  i -= 256;
  if (i < 16384) { // HB3: 64x256
    int j = i&7, f = i>>3, lane = f&63, kn = f>>6, kt = kn&7, nt = kn>>3;
    int n = nt*16 + (lane&15), k = kt*32 + ((lane>>4)<<3) + j;
    float v = 0.f;
    if (n < 36)      { if (k < 128)  v = LD<T>::get(in.p[15], n*128+k); }
    else if (n < 48) { if (k >= 128) v = LD<T>::get(in.p[23], (n-36)*128+(k-128)); }
    ((unsigned short*)(ws + OFF_HB3))[i] = f2bf(v); return; }
  i -= 16384;
  { int n = i; float v = 0.f;
    if (n < 36) v = LD<T>::get(in.p[16], n);
    else if (n < 48) v = LD<T>::get(in.p[24], n-36);
    ws[OFF_HB3B+n] = v; }
}

// ---------------- kernel 1: grouping with loose-ballot skip + double buffer ----------------
// Staging waves compute rot_rel once per point AND ballot the loosest mask
// (hmax=0.4 superset). Scan waves skip subchunks with a zero loose ballot —
// semantically identical (all-false ballot adds 0 to count).
template<typename T>
__global__ __launch_bounds__(256) void group_kernel(
    const void* __restrict__ seed, const void* __restrict__ pc,
    const void* __restrict__ vr, float* __restrict__ ws, int want)
{
#pragma clang fp contract(off)
  if (((const volatile int*)(ws + OFF_FLAG))[0] != want) return;
  float* feat = ws + OFF_FEAT;
  int* cnt = (int*)(ws + OFF_CNT);
  __shared__ float rxs[2][256], rys[2][256], rzs[2][256];
  __shared__ unsigned long long loose[2][4];
  int bs = blockIdx.x;
  int b = bs >> 10;
  int t = threadIdx.x;
  int wave = t >> 6, lane = t & 63;
  float sx = LD<T>::get(seed, bs*3+0), sy = LD<T>::get(seed, bs*3+1), sz = LD<T>::get(seed, bs*3+2);
  float r00=LD<T>::get(vr,bs*9+0), r01=LD<T>::get(vr,bs*9+1), r02=LD<T>::get(vr,bs*9+2);
  float r10=LD<T>::get(vr,bs*9+3), r11=LD<T>::get(vr,bs*9+4), r12=LD<T>::get(vr,bs*9+5);
  float r20=LD<T>::get(vr,bs*9+6), r21=LD<T>::get(vr,bs*9+7), r22=LD<T>::get(vr,bs*9+8);
  const float hmaxs[4] = {0.1f, 0.2f, 0.3f, 0.4f};
  float hmax = hmaxs[wave];
  int g = bs*4 + wave;
  float* fout = feat + g*192;
  int base = b*(NPTS*3);
  int count = 0;
  float p0x=0.f, p0y=0.f, p0z=0.f;

  auto stage = [&](int c0, int buf){
    int pi = base + (c0 + t)*3;
    float e0 = LD<T>::get(pc, pi+0) - sx;
    float e1 = LD<T>::get(pc, pi+1) - sy;
    float e2 = LD<T>::get(pc, pi+2) - sz;
    float rx = e0*r00 + e1*r10 + e2*r20;
    float ry = e0*r01 + e1*r11 + e2*r21;
    float rz = e0*r02 + e1*r12 + e2*r22;
    rxs[buf][t] = rx; rys[buf][t] = ry; rzs[buf][t] = rz;
    float r2 = ry*ry + rz*rz;
    bool lm = (rx > -0.2f) && (rx < 0.4f) && (r2 < 0.09f);
    unsigned long long bal = __ballot(lm);
    if (lane == 0) loose[buf][wave] = bal;
  };

  stage(0, 0);
  for (int c = 0; c < NPTS/256; ++c) {
    int buf = c & 1;
    __syncthreads();
    if (c == 0) { p0x = rxs[0][0]; p0y = rys[0][0]; p0z = rzs[0][0]; }
    if (c + 1 < NPTS/256) stage((c+1)*256, 1 - buf);
    if (count < 64) {   // wave-uniform
      for (int sub = 0; sub < 4; ++sub) {
        unsigned long long lb = loose[buf][sub];
        if (lb == 0ull) continue;         // no candidate anywhere in subchunk
        int idx = sub*64 + lane;
        float rx = rxs[buf][idx], ry = rys[buf][idx], rz = rzs[buf][idx];
        float r2 = ry*ry + rz*rz;
        bool m = (rx > -0.2f) && (rx < hmax) && (r2 < 0.09f);
        unsigned long long bal = __ballot(m);
        int rank = __popcll(bal & ((1ull << lane) - 1ull));
        int slot = count + rank;
        if (m && slot < 64) { fout[slot*3+0]=rx; fout[slot*3+1]=ry; fout[slot*3+2]=rz; }
        count += __popcll(bal);
      }
    }
  }
  if (count == 0) {
    if (lane == 0) { fout[0]=p0x; fout[1]=p0y; fout[2]=p0z; }
    count = 1;
  }
  if (lane == 0) cnt[g] = (count > 64) ? 64 : count;
}

// ---------------- kernel 2: SharedMLP + maxpool, dynamic row tiles ----------------
// MT = ceil(V/16): only tiles holding real samples are computed. Rows in
// [V, MT*16) are garbage-but-finite (poison = -3e-13) and masked in maxpool.
__global__ __launch_bounds__(256) void mlp_kernel(float* __restrict__ ws){
  __shared__ unsigned short h2s[2][64*136];
  __shared__ float w1q[4][256];
  const int t = threadIdx.x;
  const int wave = t >> 6, lane = t & 63;
  const int quad = lane >> 4, l15 = lane & 15;
  const int grp = wave >> 1, nhalf = wave & 1;
  const int g = blockIdx.x*2 + grp;
  for (int i = t; i < 1024; i += 256) w1q[i>>8][i&255] = ws[OFF_W1Q + (i&255)];
  const int V = ((const int*)(ws + OFF_CNT))[g];
  const int MT = (V + 15) >> 4;          // 1..4, wave-uniform
  const float* feat = ws + OFF_FEAT + g*192;
  __syncthreads();
  bf16x8 a1[4][2];
  const float* wq = w1q[quad];
#pragma unroll
  for (int mt = 0; mt < 4; ++mt) if (mt < MT) {
    const int m = mt*16 + l15;
    const float x0 = feat[m*3+0], x1 = feat[m*3+1], x2 = feat[m*3+2];
#pragma unroll
    for (int kt = 0; kt < 2; ++kt) {
      const int c0 = kt*32 + quad*8;
#pragma unroll
      for (int j = 0; j < 8; ++j) {
        const float* w = wq + (c0+j)*4;
        a1[mt][kt][j] = (short)f2bf(fmaxf(w[3] + x0*w[0] + x1*w[1] + x2*w[2], 0.f));
      }
    }
  }
  unsigned short* h2 = h2s[grp];
  const bf16x8* BW2 = (const bf16x8*)(ws + OFF_BW2);
#pragma unroll
  for (int nt4 = 0; nt4 < 4; ++nt4) {
    const int nt = nhalf*4 + nt4;
    const int n = nt*16 + l15;
    const float bias = ws[OFF_B2 + n];
    f32x4 acc[4];
#pragma unroll
    for (int mt = 0; mt < 4; ++mt) if (mt < MT) acc[mt] = (f32x4){bias, bias, bias, bias};
#pragma unroll
    for (int kt = 0; kt < 2; ++kt) {
      const bf16x8 b = BW2[(nt*2+kt)*64 + lane];
#pragma unroll
      for (int mt = 0; mt < 4; ++mt) if (mt < MT)
        acc[mt] = __builtin_amdgcn_mfma_f32_16x16x32_bf16(a1[mt][kt], b, acc[mt], 0, 0, 0);
    }
#pragma unroll
    for (int mt = 0; mt < 4; ++mt) if (mt < MT)
#pragma unroll
      for (int jj = 0; jj < 4; ++jj) {
        const int m = mt*16 + quad*4 + jj;
        h2[m*136 + n] = f2bf(fmaxf(acc[mt][jj], 0.f));
      }
  }
  __syncthreads();
  bf16x8 a2[4][4];
#pragma unroll
  for (int mt = 0; mt < 4; ++mt) if (mt < MT)
#pragma unroll
    for (int kt = 0; kt < 4; ++kt)
      a2[mt][kt] = *(const bf16x8*)&h2[(mt*16 + l15)*136 + kt*32 + quad*8];
  const bf16x8* BW3 = (const bf16x8*)(ws + OFF_BW3);
  float vpv[8];
#pragma unroll
  for (int nt8 = 0; nt8 < 8; ++nt8) {
    const int nt = nhalf*8 + nt8;
    const int n = nt*16 + l15;
    const float bias = ws[OFF_B3 + n];
    f32x4 acc[4];
#pragma unroll
    for (int mt = 0; mt < 4; ++mt) if (mt < MT) acc[mt] = (f32x4){bias, bias, bias, bias};
#pragma unroll
    for (int kt = 0; kt < 4; ++kt) {
      const bf16x8 b = BW3[(nt*4+kt)*64 + lane];
#pragma unroll
      for (int mt = 0; mt < 4; ++mt) if (mt < MT)
        acc[mt] = __builtin_amdgcn_mfma_f32_16x16x32_bf16(a2[mt][kt], b, acc[mt], 0, 0, 0);
    }
    float mx = 0.f;
#pragma unroll
    for (int mt = 0; mt < 4; ++mt) if (mt < MT)
#pragma unroll
      for (int jj = 0; jj < 4; ++jj) {
        const int row = mt*16 + quad*4 + jj;
        const float v = fmaxf(acc[mt][jj], 0.f);
        mx = (row < V) ? fmaxf(mx, v) : mx;
      }
    mx = fmaxf(mx, __shfl_xor(mx, 16, 64));
    mx = fmaxf(mx, __shfl_xor(mx, 32, 64));
    vpv[nt8] = mx;
  }
  if (quad == 0) {
    float* vp = ws + OFF_VP + g*256 + nhalf*128;
#pragma unroll
    for (int nt8 = 0; nt8 < 8; ++nt8) vp[nt8*16 + l15] = vpv[nt8];
  }
}

// ---------------- kernel 3: heads via bf16 MFMA, fused transpose write ----------------
#define YSTRIDE 264
template<typename OUT>
__global__ __launch_bounds__(256) void heads_kernel(float* __restrict__ ws, OUT* __restrict__ out, int want){
  if (((const volatile int*)(ws + OFF_FLAG))[0] != want) return;
  __shared__ unsigned short y[16*YSTRIDE];
  const int t = threadIdx.x;
  const int wave = t >> 6, lane = t & 63;
  const int quad = lane >> 4, l15 = lane & 15;
  const int r0 = blockIdx.x * 16;
  bf16x8 a[8];
  const float* vp = ws + OFF_VP + (r0 + l15)*256;
#pragma unroll
  for (int kt = 0; kt < 8; ++kt) {
    const float4* v4 = (const float4*)(vp + kt*32 + quad*8);
    float4 u0 = v4[0], u1 = v4[1];
    a[kt][0]=(short)f2bf(u0.x); a[kt][1]=(short)f2bf(u0.y); a[kt][2]=(short)f2bf(u0.z); a[kt][3]=(short)f2bf(u0.w);
    a[kt][4]=(short)f2bf(u1.x); a[kt][5]=(short)f2bf(u1.y); a[kt][6]=(short)f2bf(u1.z); a[kt][7]=(short)f2bf(u1.w);
  }
  const bf16x8* HB1 = (const bf16x8*)(ws + OFF_HB1);
#pragma unroll
  for (int nt4 = 0; nt4 < 4; ++nt4) {
    const int nt = wave*4 + nt4;
    const int n = nt*16 + l15;
    const float bias = ws[OFF_HB1B + n];
    f32x4 acc = (f32x4){bias, bias, bias, bias};
#pragma unroll
    for (int kt = 0; kt < 8; ++kt)
      acc = __builtin_amdgcn_mfma_f32_16x16x32_bf16(a[kt], HB1[(nt*8+kt)*64 + lane], acc, 0, 0, 0);
#pragma unroll
    for (int jj = 0; jj < 4; ++jj)
      y[(quad*4+jj)*YSTRIDE + n] = f2bf(fmaxf(acc[jj], 0.f));
  }
  __syncthreads();
#pragma unroll
  for (int kt = 0; kt < 8; ++kt)
    a[kt] = *(const bf16x8*)&y[l15*YSTRIDE + kt*32 + quad*8];
  __syncthreads();
  const bf16x8* HB2 = (const bf16x8*)(ws + OFF_HB2);
#pragma unroll
  for (int nt4 = 0; nt4 < 4; ++nt4) {
    const int nt = wave*4 + nt4;
    const int n = nt*16 + l15;
    const float bias = ws[OFF_HB2B + n];
    f32x4 acc = (f32x4){bias, bias, bias, bias};
#pragma unroll
    for (int kt = 0; kt < 8; ++kt)
      acc = __builtin_amdgcn_mfma_f32_16x16x32_bf16(a[kt], HB2[(nt*8+kt)*64 + lane], acc, 0, 0, 0);
#pragma unroll
    for (int jj = 0; jj < 4; ++jj)
      y[(quad*4+jj)*YSTRIDE + n] = f2bf(fmaxf(acc[jj], 0.f));
  }
  __syncthreads();
#pragma unroll
  for (int kt = 0; kt < 8; ++kt)
    a[kt] = *(const bf16x8*)&y[l15*YSTRIDE + kt*32 + quad*8];
  const bf16x8* HB3 = (const bf16x8*)(ws + OFF_HB3);
  {
    const int n = wave*16 + l15;
    const float bias = ws[OFF_HB3B + n];
    f32x4 acc = (f32x4){bias, bias, bias, bias};
#pragma unroll
    for (int kt = 0; kt < 8; ++kt)
      acc = __builtin_amdgcn_mfma_f32_16x16x32_bf16(a[kt], HB3[(wave*8+kt)*64 + lane], acc, 0, 0, 0);
    if (n < 48) {
#pragma unroll
      for (int jj = 0; jj < 4; ++jj) {
        const int gr = r0 + quad*4 + jj;
        const int b = gr >> 12, rem = gr & 4095, s = rem >> 2, d = rem & 3;
        out[((b*48 + n)*1024 + s)*4 + d] = (OUT)acc[jj];
      }
    }
  }
}

extern "C" void kernel_launch(void* const* d_in, const int* in_sizes, int n_in,
                              void* d_out, int out_size, void* d_ws, size_t ws_size,
                              hipStream_t stream) {
  float* ws = (float*)d_ws;
  Ptrs P;
  for (int i = 0; i < 25; ++i) P.p[i] = d_in[i];
  detect_kernel<<<1, 256, 0, stream>>>(d_in[5], d_in[7], (int*)(ws + OFF_FLAG));
  prep_kernel<__hip_bfloat16><<<(PREP_TOTAL+255)/256, 256, 0, stream>>>(P, ws, 0);
  prep_kernel<float><<<(PREP_TOTAL+255)/256, 256, 0, stream>>>(P, ws, 1);
  group_kernel<__hip_bfloat16><<<NB*NS, 256, 0, stream>>>(d_in[0], d_in[1], d_in[2], ws, 0);
  group_kernel<float><<<NB*NS, 256, 0, stream>>>(d_in[0], d_in[1], d_in[2], ws, 1);
  mlp_kernel<<<NGROUP/2, 256, 0, stream>>>(ws);
  heads_kernel<__hip_bfloat16><<<NGROUP/16, 256, 0, stream>>>(ws, (__hip_bfloat16*)d_out, 0);
  heads_kernel<float><<<NGROUP/16, 256, 0, stream>>>(ws, (float*)d_out, 1);
}

// Round 6
// 260.189 us; speedup vs baseline: 1.3717x; 1.3717x over previous
//
#include <hip/hip_runtime.h>
#include <hip/hip_bf16.h>

// ---------------- problem constants ----------------
#define NB    2
#define NS    1024
#define NPTS  8192
#define NGROUP (NB*NS*4)   // 8192 groups = rows

// ---------------- ws layout (float offsets) ----------------
enum : int {
  OFF_BW2  = 256,      // 8192 bf16: W2 folded, B-frag order
  OFF_W1Q  = 4352,     // 64 x float4 (w0,w1,w2,b) folded L1
  OFF_B2   = 8448,     // 128 f32
  OFF_BW3  = 8576,     // 32768 bf16: W3 folded, B-frag order
  OFF_B3   = 41344,    // 256 f32
  OFF_HB1  = 41600,    // 65536 bf16: combined head L1 (256x256), B-frag order
  OFF_HB1B = 74368,    // 256 f32
  OFF_HB2  = 74624,    // 65536 bf16: combined head L2 (256x256 block-diag)
  OFF_HB2B = 107392,   // 256 f32
  OFF_HB3  = 107648,   // 16384 bf16: combined head L3 (64x256 block-struct)
  OFF_HB3B = 115840,   // 64 f32
  PREP_TOTAL = 189632, // work items in prep
  OFF_FEAT = 146688,            // 8192 * 64 * 3
  OFF_VP   = 1719552,           // 8192 * 256
  OFF_CNT  = 3816704,           // 8192 ints
  OFF_FLAG = 3824896,           // 1 int: 0 = bf16 inputs, 1 = fp32 inputs
};

struct Ptrs { const void* p[25]; };

typedef __attribute__((ext_vector_type(8))) short bf16x8;
typedef __attribute__((ext_vector_type(4))) float f32x4;

template<typename T> struct LD;
template<> struct LD<float> {
  static __device__ __forceinline__ float get(const void* p, int i){ return ((const float*)p)[i]; }
};
template<> struct LD<__hip_bfloat16> {
  static __device__ __forceinline__ float get(const void* p, int i){ return __bfloat162float(((const __hip_bfloat16*)p)[i]); }
};

template<typename T>
__device__ __forceinline__ float bnscale(const void* bn, int C, int c){
  float g = LD<T>::get(bn, c);
  float v = LD<T>::get(bn, 3*C + c);
  return g / sqrtf(v + 1e-5f);
}

__device__ __forceinline__ unsigned short f2bf(float v){
  __hip_bfloat16 hb = __float2bfloat16(v);
  return *reinterpret_cast<unsigned short*>(&hb);
}

// ---------------- kernel -1: detect input dtype ----------------
__global__ __launch_bounds__(256) void detect_kernel(const void* w2, const void* w3, int* flag){
  __shared__ int f;
  int t = threadIdx.x;
  if (t == 0) f = 0;
  __syncthreads();
  int loc = 0;
  const unsigned short* a = (const unsigned short*)w2;
  for (int i = t; i < 8192; i += 256)  loc |= ((a[i] & 0x7F80) == 0x7F80);
  const unsigned short* b = (const unsigned short*)w3;
  for (int i = t; i < 32768; i += 256) loc |= ((b[i] & 0x7F80) == 0x7F80);
  if (loc) atomicOr(&f, 1);
  __syncthreads();
  if (t == 0) flag[0] = f;
}

// ---------------- prep body: fold BN; swizzle weights to bf16 B-frags ----------------
template<typename T>
__device__ void prep_body(const Ptrs& in, float* __restrict__ ws, int i){
  if (i < 256) { int c = i>>2, d = i&3; float s = bnscale<T>(in.p[4],64,c);
    float v = (d<3) ? LD<T>::get(in.p[3], c*3+d)*s
                    : LD<T>::get(in.p[4],64+c) - LD<T>::get(in.p[4],2*64+c)*s;
    ws[OFF_W1Q+i] = v; return; }
  i -= 256;
  if (i < 8192) { // BW2: 128x64, KT=2
    int j = i&7, f = i>>3, lane = f&63, kn = f>>6, kt = kn&1, nt = kn>>1;
    int n = nt*16 + (lane&15), k = kt*32 + ((lane>>4)<<3) + j;
    float s = bnscale<T>(in.p[6],128,n);
    ((unsigned short*)(ws + OFF_BW2))[i] = f2bf(LD<T>::get(in.p[5], n*64+k)*s); return; }
  i -= 8192;
  if (i < 32768) { // BW3: 256x128, KT=4
    int j = i&7, f = i>>3, lane = f&63, kn = f>>6, kt = kn&3, nt = kn>>2;
    int n = nt*16 + (lane&15), k = kt*32 + ((lane>>4)<<3) + j;
    float s = bnscale<T>(in.p[8],256,n);
    ((unsigned short*)(ws + OFF_BW3))[i] = f2bf(LD<T>::get(in.p[7], n*128+k)*s); return; }
  i -= 32768;
  if (i < 128) { float s = bnscale<T>(in.p[6],128,i);
    ws[OFF_B2+i] = LD<T>::get(in.p[6],128+i) - LD<T>::get(in.p[6],2*128+i)*s; return; }
  i -= 128;
  if (i < 256) { float s = bnscale<T>(in.p[8],256,i);
    ws[OFF_B3+i] = LD<T>::get(in.p[8],256+i) - LD<T>::get(in.p[8],2*256+i)*s; return; }
  i -= 256;
  if (i < 65536) { // HB1: combined 256x256, KT=8
    int j = i&7, f = i>>3, lane = f&63, kn = f>>6, kt = kn&7, nt = kn>>3;
    int n = nt*16 + (lane&15), k = kt*32 + ((lane>>4)<<3) + j;
    float v;
    if (n < 128) v = LD<T>::get(in.p[9],  n*256+k)       * bnscale<T>(in.p[11],128,n);
    else         v = LD<T>::get(in.p[17], (n-128)*256+k) * bnscale<T>(in.p[19],128,n-128);
    ((unsigned short*)(ws + OFF_HB1))[i] = f2bf(v); return; }
  i -= 65536;
  if (i < 256) { int n = i; float v;
    if (n < 128) { float s = bnscale<T>(in.p[11],128,n);
      v = (LD<T>::get(in.p[10],n) - LD<T>::get(in.p[11],2*128+n))*s + LD<T>::get(in.p[11],128+n); }
    else { int m = n-128; float s = bnscale<T>(in.p[19],128,m);
      v = (LD<T>::get(in.p[18],m) - LD<T>::get(in.p[19],2*128+m))*s + LD<T>::get(in.p[19],128+m); }
    ws[OFF_HB1B+n] = v; return; }
  i -= 256;
  if (i < 65536) { // HB2: 256x256 block-diagonal
    int j = i&7, f = i>>3, lane = f&63, kn = f>>6, kt = kn&7, nt = kn>>3;
    int n = nt*16 + (lane&15), k = kt*32 + ((lane>>4)<<3) + j;
    float v = 0.f;
    if (n < 128) { if (k < 128)  v = LD<T>::get(in.p[12], n*128+k)            * bnscale<T>(in.p[14],128,n); }
    else         { if (k >= 128) v = LD<T>::get(in.p[20], (n-128)*128+(k-128)) * bnscale<T>(in.p[22],128,n-128); }
    ((unsigned short*)(ws + OFF_HB2))[i] = f2bf(v); return; }
  i -= 65536;
  if (i < 256) { int n = i; float v;
    if (n < 128) { float s = bnscale<T>(in.p[14],128,n);
      v = (LD<T>::get(in.p[13],n) - LD<T>::get(in.p[14],2*128+n))*s + LD<T>::get(in.p[14],128+n); }
    else { int m = n-128; float s = bnscale<T>(in.p[22],128,m);
      v = (LD<T>::get(in.p[21],m) - LD<T>::get(in.p[22],2*128+m))*s + LD<T>::get(in.p[22],128+m); }
    ws[OFF_HB2B+n] = v; return; }
  i -= 256;
  if (i < 16384) { // HB3: 64x256
    int j = i&7, f = i>>3, lane = f&63, kn = f>>6, kt = kn&7, nt = kn>>3;
    int n = nt*16 + (lane&15), k = kt*32 + ((lane>>4)<<3) + j;
    float v = 0.f;
    if (n < 36)      { if (k < 128)  v = LD<T>::get(in.p[15], n*128+k); }
    else if (n < 48) { if (k >= 128) v = LD<T>::get(in.p[23], (n-36)*128+(k-128)); }
    ((unsigned short*)(ws + OFF_HB3))[i] = f2bf(v); return; }
  i -= 16384;
  { int n = i; float v = 0.f;
    if (n < 36) v = LD<T>::get(in.p[16], n);
    else if (n < 48) v = LD<T>::get(in.p[24], n-36);
    ws[OFF_HB3B+n] = v; }
}

__global__ __launch_bounds__(256) void prep_kernel(Ptrs in, float* __restrict__ ws){
  int i = blockIdx.x*256 + threadIdx.x;
  if (i >= PREP_TOTAL) return;
  if (((const volatile int*)(ws + OFF_FLAG))[0]) prep_body<float>(in, ws, i);
  else                                           prep_body<__hip_bfloat16>(in, ws, i);
}

// ---------------- group: one wave per seed, all 4 depth bins per scan ----------------
// No LDS, no barriers. Rotation computed once per point; the 4 bin masks share
// rx/r2 and differ only in the hmax compare (exact same fp32 values/order as
// previous verified rounds => identical masks).
template<typename T>
__device__ void group_body(const void* __restrict__ seed, const void* __restrict__ pc,
                           float* __restrict__ ws, const void* __restrict__ vr, int bs){
#pragma clang fp contract(off)
  float* feat = ws + OFF_FEAT;
  int* cnt = (int*)(ws + OFF_CNT);
  const int lane = threadIdx.x & 63;
  const int b = bs >> 10;
  float sx = LD<T>::get(seed, bs*3+0), sy = LD<T>::get(seed, bs*3+1), sz = LD<T>::get(seed, bs*3+2);
  float r00=LD<T>::get(vr,bs*9+0), r01=LD<T>::get(vr,bs*9+1), r02=LD<T>::get(vr,bs*9+2);
  float r10=LD<T>::get(vr,bs*9+3), r11=LD<T>::get(vr,bs*9+4), r12=LD<T>::get(vr,bs*9+5);
  float r20=LD<T>::get(vr,bs*9+6), r21=LD<T>::get(vr,bs*9+7), r22=LD<T>::get(vr,bs*9+8);
  float* f0 = feat + (bs*4+0)*192;
  float* f1 = feat + (bs*4+1)*192;
  float* f2 = feat + (bs*4+2)*192;
  float* f3 = feat + (bs*4+3)*192;
  int c0n=0, c1n=0, c2n=0, c3n=0;
  const int base = b*(NPTS*3);
  float p0x=0.f, p0y=0.f, p0z=0.f;
  for (int c = 0; c < NPTS/64; ++c) {
    const int pi = base + (c*64 + lane)*3;
    float e0 = LD<T>::get(pc, pi+0) - sx;
    float e1 = LD<T>::get(pc, pi+1) - sy;
    float e2 = LD<T>::get(pc, pi+2) - sz;
    float rx = e0*r00 + e1*r10 + e2*r20;
    float ry = e0*r01 + e1*r11 + e2*r21;
    float rz = e0*r02 + e1*r12 + e2*r22;
    float r2 = ry*ry + rz*rz;
    if (c == 0 && lane == 0) { p0x = rx; p0y = ry; p0z = rz; }
    const bool mb = (rx > -0.2f) && (r2 < 0.09f);
    const unsigned long long pm = (1ull << lane) - 1ull;
    { bool m = mb && (rx < 0.1f); unsigned long long bal = __ballot(m);
      if (bal) { int slot = c0n + __popcll(bal & pm);
        if (m && slot < 64) { f0[slot*3]=rx; f0[slot*3+1]=ry; f0[slot*3+2]=rz; }
        c0n += __popcll(bal); } }
    { bool m = mb && (rx < 0.2f); unsigned long long bal = __ballot(m);
      if (bal) { int slot = c1n + __popcll(bal & pm);
        if (m && slot < 64) { f1[slot*3]=rx; f1[slot*3+1]=ry; f1[slot*3+2]=rz; }
        c1n += __popcll(bal); } }
    { bool m = mb && (rx < 0.3f); unsigned long long bal = __ballot(m);
      if (bal) { int slot = c2n + __popcll(bal & pm);
        if (m && slot < 64) { f2[slot*3]=rx; f2[slot*3+1]=ry; f2[slot*3+2]=rz; }
        c2n += __popcll(bal); } }
    { bool m = mb && (rx < 0.4f); unsigned long long bal = __ballot(m);
      if (bal) { int slot = c3n + __popcll(bal & pm);
        if (m && slot < 64) { f3[slot*3]=rx; f3[slot*3+1]=ry; f3[slot*3+2]=rz; }
        c3n += __popcll(bal); } }
  }
  if (lane == 0) {
    if (c0n == 0) { f0[0]=p0x; f0[1]=p0y; f0[2]=p0z; c0n = 1; }
    if (c1n == 0) { f1[0]=p0x; f1[1]=p0y; f1[2]=p0z; c1n = 1; }
    if (c2n == 0) { f2[0]=p0x; f2[1]=p0y; f2[2]=p0z; c2n = 1; }
    if (c3n == 0) { f3[0]=p0x; f3[1]=p0y; f3[2]=p0z; c3n = 1; }
    cnt[bs*4+0] = (c0n > 64) ? 64 : c0n;
    cnt[bs*4+1] = (c1n > 64) ? 64 : c1n;
    cnt[bs*4+2] = (c2n > 64) ? 64 : c2n;
    cnt[bs*4+3] = (c3n > 64) ? 64 : c3n;
  }
}

__global__ __launch_bounds__(256) void group_kernel(
    const void* __restrict__ seed, const void* __restrict__ pc,
    const void* __restrict__ vr, float* __restrict__ ws)
{
  const int bs = blockIdx.x*4 + (threadIdx.x >> 6);   // one wave per seed
  if (((const volatile int*)(ws + OFF_FLAG))[0]) group_body<float>(seed, pc, ws, vr, bs);
  else                                           group_body<__hip_bfloat16>(seed, pc, ws, vr, bs);
}

// ---------------- kernel 2: SharedMLP + maxpool via bf16 MFMA (R4-verified, static) ----------------
__global__ __launch_bounds__(256) void mlp_kernel(float* __restrict__ ws){
  __shared__ unsigned short h2s[2][64*136];
  __shared__ float w1q[4][256];
  const int t = threadIdx.x;
  const int wave = t >> 6, lane = t & 63;
  const int quad = lane >> 4, l15 = lane & 15;
  const int grp = wave >> 1, nhalf = wave & 1;
  const int g = blockIdx.x*2 + grp;
  for (int i = t; i < 1024; i += 256) w1q[i>>8][i&255] = ws[OFF_W1Q + (i&255)];
  const int V = ((const int*)(ws + OFF_CNT))[g];
  const float* feat = ws + OFF_FEAT + g*192;
  __syncthreads();
  bf16x8 a1[4][2];
  const float* wq = w1q[quad];
#pragma unroll
  for (int mt = 0; mt < 4; ++mt) {
    const int m = mt*16 + l15;
    const float x0 = feat[m*3+0], x1 = feat[m*3+1], x2 = feat[m*3+2];
#pragma unroll
    for (int kt = 0; kt < 2; ++kt) {
      const int c0 = kt*32 + quad*8;
#pragma unroll
      for (int j = 0; j < 8; ++j) {
        const float* w = wq + (c0+j)*4;
        a1[mt][kt][j] = (short)f2bf(fmaxf(w[3] + x0*w[0] + x1*w[1] + x2*w[2], 0.f));
      }
    }
  }
  unsigned short* h2 = h2s[grp];
  const bf16x8* BW2 = (const bf16x8*)(ws + OFF_BW2);
#pragma unroll
  for (int nt4 = 0; nt4 < 4; ++nt4) {
    const int nt = nhalf*4 + nt4;
    const int n = nt*16 + l15;
    const float bias = ws[OFF_B2 + n];
    f32x4 acc[4];
#pragma unroll
    for (int mt = 0; mt < 4; ++mt) acc[mt] = (f32x4){bias, bias, bias, bias};
#pragma unroll
    for (int kt = 0; kt < 2; ++kt) {
      const bf16x8 b = BW2[(nt*2+kt)*64 + lane];
#pragma unroll
      for (int mt = 0; mt < 4; ++mt)
        acc[mt] = __builtin_amdgcn_mfma_f32_16x16x32_bf16(a1[mt][kt], b, acc[mt], 0, 0, 0);
    }
#pragma unroll
    for (int mt = 0; mt < 4; ++mt)
#pragma unroll
      for (int jj = 0; jj < 4; ++jj) {
        const int m = mt*16 + quad*4 + jj;
        h2[m*136 + n] = f2bf(fmaxf(acc[mt][jj], 0.f));
      }
  }
  __syncthreads();
  bf16x8 a2[4][4];
#pragma unroll
  for (int mt = 0; mt < 4; ++mt)
#pragma unroll
    for (int kt = 0; kt < 4; ++kt)
      a2[mt][kt] = *(const bf16x8*)&h2[(mt*16 + l15)*136 + kt*32 + quad*8];
  const bf16x8* BW3 = (const bf16x8*)(ws + OFF_BW3);
  float vpv[8];
#pragma unroll
  for (int nt8 = 0; nt8 < 8; ++nt8) {
    const int nt = nhalf*8 + nt8;
    const int n = nt*16 + l15;
    const float bias = ws[OFF_B3 + n];
    f32x4 acc[4];
#pragma unroll
    for (int mt = 0; mt < 4; ++mt) acc[mt] = (f32x4){bias, bias, bias, bias};
#pragma unroll
    for (int kt = 0; kt < 4; ++kt) {
      const bf16x8 b = BW3[(nt*4+kt)*64 + lane];
#pragma unroll
      for (int mt = 0; mt < 4; ++mt)
        acc[mt] = __builtin_amdgcn_mfma_f32_16x16x32_bf16(a2[mt][kt], b, acc[mt], 0, 0, 0);
    }
    float mx = 0.f;
#pragma unroll
    for (int mt = 0; mt < 4; ++mt)
#pragma unroll
      for (int jj = 0; jj < 4; ++jj) {
        const int row = mt*16 + quad*4 + jj;
        const float v = fmaxf(acc[mt][jj], 0.f);
        mx = (row < V) ? fmaxf(mx, v) : mx;
      }
    mx = fmaxf(mx, __shfl_xor(mx, 16, 64));
    mx = fmaxf(mx, __shfl_xor(mx, 32, 64));
    vpv[nt8] = mx;
  }
  if (quad == 0) {
    float* vp = ws + OFF_VP + g*256 + nhalf*128;
#pragma unroll
    for (int nt8 = 0; nt8 < 8; ++nt8) vp[nt8*16 + l15] = vpv[nt8];
  }
}

// ---------------- kernel 3: heads via bf16 MFMA, fused transpose write ----------------
#define YSTRIDE 264
__global__ __launch_bounds__(256) void heads_kernel(float* __restrict__ ws, void* __restrict__ outv){
  const int isf32 = ((const volatile int*)(ws + OFF_FLAG))[0];
  __shared__ unsigned short y[16*YSTRIDE];
  const int t = threadIdx.x;
  const int wave = t >> 6, lane = t & 63;
  const int quad = lane >> 4, l15 = lane & 15;
  const int r0 = blockIdx.x * 16;
  bf16x8 a[8];
  const float* vp = ws + OFF_VP + (r0 + l15)*256;
#pragma unroll
  for (int kt = 0; kt < 8; ++kt) {
    const float4* v4 = (const float4*)(vp + kt*32 + quad*8);
    float4 u0 = v4[0], u1 = v4[1];
    a[kt][0]=(short)f2bf(u0.x); a[kt][1]=(short)f2bf(u0.y); a[kt][2]=(short)f2bf(u0.z); a[kt][3]=(short)f2bf(u0.w);
    a[kt][4]=(short)f2bf(u1.x); a[kt][5]=(short)f2bf(u1.y); a[kt][6]=(short)f2bf(u1.z); a[kt][7]=(short)f2bf(u1.w);
  }
  const bf16x8* HB1 = (const bf16x8*)(ws + OFF_HB1);
#pragma unroll
  for (int nt4 = 0; nt4 < 4; ++nt4) {
    const int nt = wave*4 + nt4;
    const int n = nt*16 + l15;
    const float bias = ws[OFF_HB1B + n];
    f32x4 acc = (f32x4){bias, bias, bias, bias};
#pragma unroll
    for (int kt = 0; kt < 8; ++kt)
      acc = __builtin_amdgcn_mfma_f32_16x16x32_bf16(a[kt], HB1[(nt*8+kt)*64 + lane], acc, 0, 0, 0);
#pragma unroll
    for (int jj = 0; jj < 4; ++jj)
      y[(quad*4+jj)*YSTRIDE + n] = f2bf(fmaxf(acc[jj], 0.f));
  }
  __syncthreads();
#pragma unroll
  for (int kt = 0; kt < 8; ++kt)
    a[kt] = *(const bf16x8*)&y[l15*YSTRIDE + kt*32 + quad*8];
  __syncthreads();
  const bf16x8* HB2 = (const bf16x8*)(ws + OFF_HB2);
#pragma unroll
  for (int nt4 = 0; nt4 < 4; ++nt4) {
    const int nt = wave*4 + nt4;
    const int n = nt*16 + l15;
    const float bias = ws[OFF_HB2B + n];
    f32x4 acc = (f32x4){bias, bias, bias, bias};
#pragma unroll
    for (int kt = 0; kt < 8; ++kt)
      acc = __builtin_amdgcn_mfma_f32_16x16x32_bf16(a[kt], HB2[(nt*8+kt)*64 + lane], acc, 0, 0, 0);
#pragma unroll
    for (int jj = 0; jj < 4; ++jj)
      y[(quad*4+jj)*YSTRIDE + n] = f2bf(fmaxf(acc[jj], 0.f));
  }
  __syncthreads();
#pragma unroll
  for (int kt = 0; kt < 8; ++kt)
    a[kt] = *(const bf16x8*)&y[l15*YSTRIDE + kt*32 + quad*8];
  const bf16x8* HB3 = (const bf16x8*)(ws + OFF_HB3);
  {
    const int n = wave*16 + l15;
    const float bias = ws[OFF_HB3B + n];
    f32x4 acc = (f32x4){bias, bias, bias, bias};
#pragma unroll
    for (int kt = 0; kt < 8; ++kt)
      acc = __builtin_amdgcn_mfma_f32_16x16x32_bf16(a[kt], HB3[(wave*8+kt)*64 + lane], acc, 0, 0, 0);
    if (n < 48) {
#pragma unroll
      for (int jj = 0; jj < 4; ++jj) {
        const int gr = r0 + quad*4 + jj;
        const int b = gr >> 12, rem = gr & 4095, s = rem >> 2, d = rem & 3;
        const int o = ((b*48 + n)*1024 + s)*4 + d;
        if (isf32) ((float*)outv)[o] = acc[jj];
        else       ((__hip_bfloat16*)outv)[o] = __float2bfloat16(acc[jj]);
      }
    }
  }
}

extern "C" void kernel_launch(void* const* d_in, const int* in_sizes, int n_in,
                              void* d_out, int out_size, void* d_ws, size_t ws_size,
                              hipStream_t stream) {
  float* ws = (float*)d_ws;
  Ptrs P;
  for (int i = 0; i < 25; ++i) P.p[i] = d_in[i];
  detect_kernel<<<1, 256, 0, stream>>>(d_in[5], d_in[7], (int*)(ws + OFF_FLAG));
  prep_kernel<<<(PREP_TOTAL+255)/256, 256, 0, stream>>>(P, ws);
  group_kernel<<<NB*NS/4, 256, 0, stream>>>(d_in[0], d_in[1], d_in[2], ws);
  mlp_kernel<<<NGROUP/2, 256, 0, stream>>>(ws);
  heads_kernel<<<NGROUP/16, 256, 0, stream>>>(ws, d_out);
}

// Round 7
// 216.419 us; speedup vs baseline: 1.6491x; 1.2022x over previous
//
#include <hip/hip_runtime.h>
#include <hip/hip_bf16.h>

// ---------------- problem constants ----------------
#define NB    2
#define NS    1024
#define NPTS  8192
#define NGROUP (NB*NS*4)   // 8192 groups = rows

// ---------------- ws layout (float offsets) ----------------
enum : int {
  OFF_BW2  = 256,      // 8192 bf16: W2 folded, B-frag order
  OFF_W1Q  = 4352,     // 64 x float4 (w0,w1,w2,b) folded L1
  OFF_B2   = 8448,     // 128 f32
  OFF_BW3  = 8576,     // 32768 bf16: W3 folded, B-frag order
  OFF_B3   = 41344,    // 256 f32
  OFF_HB1  = 41600,    // 65536 bf16: combined head L1 (256x256), B-frag order
  OFF_HB1B = 74368,    // 256 f32
  OFF_HB2  = 74624,    // 65536 bf16: combined head L2 (256x256 block-diag)
  OFF_HB2B = 107392,   // 256 f32
  OFF_HB3  = 107648,   // 16384 bf16: combined head L3 (64x256 block-struct)
  OFF_HB3B = 115840,   // 64 f32
  OFF_FEAT = 146688,            // 8192 * 64 * 3
  OFF_VP   = 1719552,           // 8192 * 256 (written by mlp, read by heads)
  // --- overlaid into VP region: live only between prep and mlp ---
  OFF_PCX  = 1719552,           // 16384 f32 (2 batches x 8192)
  OFF_PCY  = 1735936,
  OFF_PCZ  = 1752320,
  OFF_SEED = 1768704,           // 6144 f32
  OFF_ROT  = 1774848,           // 18432 f32
  OFF_CNT  = 3816704,           // 8192 ints
  OFF_FLAG = 3824896,           // 1 int: 0 = bf16 inputs, 1 = fp32 inputs
  PREP_TOTAL = 189632 + 6144 + 18432 + 49152,  // = 263360
};

struct Ptrs { const void* p[25]; };

typedef __attribute__((ext_vector_type(8))) short bf16x8;
typedef __attribute__((ext_vector_type(4))) float f32x4;

template<typename T> struct LD;
template<> struct LD<float> {
  static __device__ __forceinline__ float get(const void* p, int i){ return ((const float*)p)[i]; }
};
template<> struct LD<__hip_bfloat16> {
  static __device__ __forceinline__ float get(const void* p, int i){ return __bfloat162float(((const __hip_bfloat16*)p)[i]); }
};

template<typename T>
__device__ __forceinline__ float bnscale(const void* bn, int C, int c){
  float g = LD<T>::get(bn, c);
  float v = LD<T>::get(bn, 3*C + c);
  return g / sqrtf(v + 1e-5f);
}

__device__ __forceinline__ unsigned short f2bf(float v){
  __hip_bfloat16 hb = __float2bfloat16(v);
  return *reinterpret_cast<unsigned short*>(&hb);
}

// ---------------- kernel -1: detect input dtype (uint4 loads) ----------------
__global__ __launch_bounds__(256) void detect_kernel(const void* w2, const void* w3, int* flag){
  __shared__ int f;
  int t = threadIdx.x;
  if (t == 0) f = 0;
  __syncthreads();
  int loc = 0;
  auto chk = [&](unsigned u){
    loc |= ((u & 0x7F80u) == 0x7F80u);
    loc |= (((u >> 16) & 0x7F80u) == 0x7F80u);
  };
  const uint4* a = (const uint4*)w2;           // 8192 shorts = 1024 uint4
  for (int i = t; i < 1024; i += 256) { uint4 u = a[i]; chk(u.x); chk(u.y); chk(u.z); chk(u.w); }
  const uint4* b = (const uint4*)w3;           // 32768 shorts = 4096 uint4
  for (int i = t; i < 4096; i += 256) { uint4 u = b[i]; chk(u.x); chk(u.y); chk(u.z); chk(u.w); }
  if (loc) atomicOr(&f, 1);
  __syncthreads();
  if (t == 0) flag[0] = f;
}

// ---------------- prep body: fold BN; swizzle weights; fp32 SoA geometry ----------------
template<typename T>
__device__ void prep_body(const Ptrs& in, float* __restrict__ ws, int i){
  if (i < 256) { int c = i>>2, d = i&3; float s = bnscale<T>(in.p[4],64,c);
    float v = (d<3) ? LD<T>::get(in.p[3], c*3+d)*s
                    : LD<T>::get(in.p[4],64+c) - LD<T>::get(in.p[4],2*64+c)*s;
    ws[OFF_W1Q+i] = v; return; }
  i -= 256;
  if (i < 8192) { // BW2: 128x64, KT=2
    int j = i&7, f = i>>3, lane = f&63, kn = f>>6, kt = kn&1, nt = kn>>1;
    int n = nt*16 + (lane&15), k = kt*32 + ((lane>>4)<<3) + j;
    float s = bnscale<T>(in.p[6],128,n);
    ((unsigned short*)(ws + OFF_BW2))[i] = f2bf(LD<T>::get(in.p[5], n*64+k)*s); return; }
  i -= 8192;
  if (i < 32768) { // BW3: 256x128, KT=4
    int j = i&7, f = i>>3, lane = f&63, kn = f>>6, kt = kn&3, nt = kn>>2;
    int n = nt*16 + (lane&15), k = kt*32 + ((lane>>4)<<3) + j;
    float s = bnscale<T>(in.p[8],256,n);
    ((unsigned short*)(ws + OFF_BW3))[i] = f2bf(LD<T>::get(in.p[7], n*128+k)*s); return; }
  i -= 32768;
  if (i < 128) { float s = bnscale<T>(in.p[6],128,i);
    ws[OFF_B2+i] = LD<T>::get(in.p[6],128+i) - LD<T>::get(in.p[6],2*128+i)*s; return; }
  i -= 128;
  if (i < 256) { float s = bnscale<T>(in.p[8],256,i);
    ws[OFF_B3+i] = LD<T>::get(in.p[8],256+i) - LD<T>::get(in.p[8],2*256+i)*s; return; }
  i -= 256;
  if (i < 65536) { // HB1: combined 256x256, KT=8
    int j = i&7, f = i>>3, lane = f&63, kn = f>>6, kt = kn&7, nt = kn>>3;
    int n = nt*16 + (lane&15), k = kt*32 + ((lane>>4)<<3) + j;
    float v;
    if (n < 128) v = LD<T>::get(in.p[9],  n*256+k)       * bnscale<T>(in.p[11],128,n);
    else         v = LD<T>::get(in.p[17], (n-128)*256+k) * bnscale<T>(in.p[19],128,n-128);
    ((unsigned short*)(ws + OFF_HB1))[i] = f2bf(v); return; }
  i -= 65536;
  if (i < 256) { int n = i; float v;
    if (n < 128) { float s = bnscale<T>(in.p[11],128,n);
      v = (LD<T>::get(in.p[10],n) - LD<T>::get(in.p[11],2*128+n))*s + LD<T>::get(in.p[11],128+n); }
    else { int m = n-128; float s = bnscale<T>(in.p[19],128,m);
      v = (LD<T>::get(in.p[18],m) - LD<T>::get(in.p[19],2*128+m))*s + LD<T>::get(in.p[19],128+m); }
    ws[OFF_HB1B+n] = v; return; }
  i -= 256;
  if (i < 65536) { // HB2: 256x256 block-diagonal
    int j = i&7, f = i>>3, lane = f&63, kn = f>>6, kt = kn&7, nt = kn>>3;
    int n = nt*16 + (lane&15), k = kt*32 + ((lane>>4)<<3) + j;
    float v = 0.f;
    if (n < 128) { if (k < 128)  v = LD<T>::get(in.p[12], n*128+k)            * bnscale<T>(in.p[14],128,n); }
    else         { if (k >= 128) v = LD<T>::get(in.p[20], (n-128)*128+(k-128)) * bnscale<T>(in.p[22],128,n-128); }
    ((unsigned short*)(ws + OFF_HB2))[i] = f2bf(v); return; }
  i -= 65536;
  if (i < 256) { int n = i; float v;
    if (n < 128) { float s = bnscale<T>(in.p[14],128,n);
      v = (LD<T>::get(in.p[13],n) - LD<T>::get(in.p[14],2*128+n))*s + LD<T>::get(in.p[14],128+n); }
    else { int m = n-128; float s = bnscale<T>(in.p[22],128,m);
      v = (LD<T>::get(in.p[21],m) - LD<T>::get(in.p[22],2*128+m))*s + LD<T>::get(in.p[22],128+m); }
    ws[OFF_HB2B+n] = v; return; }
  i -= 256;
  if (i < 16384) { // HB3: 64x256
    int j = i&7, f = i>>3, lane = f&63, kn = f>>6, kt = kn&7, nt = kn>>3;
    int n = nt*16 + (lane&15), k = kt*32 + ((lane>>4)<<3) + j;
    float v = 0.f;
    if (n < 36)      { if (k < 128)  v = LD<T>::get(in.p[15], n*128+k); }
    else if (n < 48) { if (k >= 128) v = LD<T>::get(in.p[23], (n-36)*128+(k-128)); }
    ((unsigned short*)(ws + OFF_HB3))[i] = f2bf(v); return; }
  i -= 16384;
  if (i < 64) { int n = i; float v = 0.f;
    if (n < 36) v = LD<T>::get(in.p[16], n);
    else if (n < 48) v = LD<T>::get(in.p[24], n-36);
    ws[OFF_HB3B+n] = v; return; }
  i -= 64;
  if (i < 6144)  { ws[OFF_SEED+i] = LD<T>::get(in.p[0], i); return; }
  i -= 6144;
  if (i < 18432) { ws[OFF_ROT+i] = LD<T>::get(in.p[2], i); return; }
  i -= 18432;
  { // pointcloud SoA: arr = i>>14 (0=x,1=y,2=z), idx = i & 16383 (= b*8192+n)
    int arr = i >> 14, idx = i & 16383;
    ws[OFF_PCX + arr*16384 + idx] = LD<T>::get(in.p[1], idx*3 + arr); }
}

__global__ __launch_bounds__(256) void prep_kernel(Ptrs in, float* __restrict__ ws){
  int i = blockIdx.x*256 + threadIdx.x;
  if (i >= PREP_TOTAL) return;
  if (((const volatile int*)(ws + OFF_FLAG))[0]) prep_body<float>(in, ws, i);
  else                                           prep_body<__hip_bfloat16>(in, ws, i);
}

// ---------------- group: 2 seeds/block, 2 waves per seed (half-scan + rank merge) ----------------
// Each wave scans half the cloud maintaining its own ordered counts per bin into
// LDS scratch; merge offsets the B-half by A's count — identical to a single
// ordered scan. fp32 SoA inputs are exact conversions; same op order as prior
// verified rounds (fp contract off) => bit-identical masks and values.
__global__ __launch_bounds__(256) void group_kernel(float* __restrict__ ws){
#pragma clang fp contract(off)
  __shared__ float scratch[2][2][4][192];   // [seed][half][bin][slot*3]
  __shared__ int   cl[2][2][4];
  __shared__ float p0s[2][3];
  const int t = threadIdx.x;
  const int wave = t >> 6, lane = t & 63;
  const int s = wave >> 1, half = wave & 1;
  const int seedIdx = blockIdx.x*2 + s;
  const int b = seedIdx >> 10;
  const float sx = ws[OFF_SEED + seedIdx*3+0];
  const float sy = ws[OFF_SEED + seedIdx*3+1];
  const float sz = ws[OFF_SEED + seedIdx*3+2];
  const float r00=ws[OFF_ROT+seedIdx*9+0], r01=ws[OFF_ROT+seedIdx*9+1], r02=ws[OFF_ROT+seedIdx*9+2];
  const float r10=ws[OFF_ROT+seedIdx*9+3], r11=ws[OFF_ROT+seedIdx*9+4], r12=ws[OFF_ROT+seedIdx*9+5];
  const float r20=ws[OFF_ROT+seedIdx*9+6], r21=ws[OFF_ROT+seedIdx*9+7], r22=ws[OFF_ROT+seedIdx*9+8];
  const float* px = ws + OFF_PCX + b*8192;
  const float* py = ws + OFF_PCY + b*8192;
  const float* pz = ws + OFF_PCZ + b*8192;
  if (half == 0 && lane == 0) {   // rot_rel of point 0 (fallback fill)
    float e0 = px[0] - sx, e1 = py[0] - sy, e2 = pz[0] - sz;
    p0s[s][0] = e0*r00 + e1*r10 + e2*r20;
    p0s[s][1] = e0*r01 + e1*r11 + e2*r21;
    p0s[s][2] = e0*r02 + e1*r12 + e2*r22;
  }
  float* s0 = scratch[s][half][0];
  float* s1 = scratch[s][half][1];
  float* s2 = scratch[s][half][2];
  float* s3 = scratch[s][half][3];
  int c0n=0, c1n=0, c2n=0, c3n=0;
  const int basept = half*4096;
  const unsigned long long pm = (1ull << lane) - 1ull;

  auto scan = [&](float x, float y, float z){
    float e0 = x - sx, e1 = y - sy, e2 = z - sz;
    float rx = e0*r00 + e1*r10 + e2*r20;
    float ry = e0*r01 + e1*r11 + e2*r21;
    float rz = e0*r02 + e1*r12 + e2*r22;
    float r2 = ry*ry + rz*rz;
    const bool mb = (rx > -0.2f) && (r2 < 0.09f);
    { bool m = mb && (rx < 0.1f); unsigned long long bal = __ballot(m);
      if (bal) { int slot = c0n + __popcll(bal & pm);
        if (m && slot < 64) { s0[slot*3]=rx; s0[slot*3+1]=ry; s0[slot*3+2]=rz; }
        c0n += __popcll(bal); } }
    { bool m = mb && (rx < 0.2f); unsigned long long bal = __ballot(m);
      if (bal) { int slot = c1n + __popcll(bal & pm);
        if (m && slot < 64) { s1[slot*3]=rx; s1[slot*3+1]=ry; s1[slot*3+2]=rz; }
        c1n += __popcll(bal); } }
    { bool m = mb && (rx < 0.3f); unsigned long long bal = __ballot(m);
      if (bal) { int slot = c2n + __popcll(bal & pm);
        if (m && slot < 64) { s2[slot*3]=rx; s2[slot*3+1]=ry; s2[slot*3+2]=rz; }
        c2n += __popcll(bal); } }
    { bool m = mb && (rx < 0.4f); unsigned long long bal = __ballot(m);
      if (bal) { int slot = c3n + __popcll(bal & pm);
        if (m && slot < 64) { s3[slot*3]=rx; s3[slot*3+1]=ry; s3[slot*3+2]=rz; }
        c3n += __popcll(bal); } }
  };

  for (int c = 0; c < 64; c += 2) {
    const int i0 = basept + c*64 + lane;
    float xA = px[i0],    yA = py[i0],    zA = pz[i0];
    float xB = px[i0+64], yB = py[i0+64], zB = pz[i0+64];
    scan(xA, yA, zA);
    scan(xB, yB, zB);
  }
  if (lane == 0) { cl[s][half][0]=c0n; cl[s][half][1]=c1n; cl[s][half][2]=c2n; cl[s][half][3]=c3n; }
  __syncthreads();
  // merge: A slots [0,ca), B slots [ca, ca+min(cb,64-ca))
  for (int idx = t; idx < 512; idx += 256) {
    const int ss = idx >> 8, rem = idx & 255, bin = rem >> 6, slot = rem & 63;
    int ca = cl[ss][0][bin]; if (ca > 64) ca = 64;
    int cb = cl[ss][1][bin];
    const int g = (blockIdx.x*2 + ss)*4 + bin;
    float* fo = ws + OFF_FEAT + g*192;
    if (slot < ca) {
      fo[slot*3+0] = scratch[ss][0][bin][slot*3+0];
      fo[slot*3+1] = scratch[ss][0][bin][slot*3+1];
      fo[slot*3+2] = scratch[ss][0][bin][slot*3+2];
    }
    int nb = 64 - ca; if (cb < nb) nb = cb;
    if (slot < nb) {
      fo[(ca+slot)*3+0] = scratch[ss][1][bin][slot*3+0];
      fo[(ca+slot)*3+1] = scratch[ss][1][bin][slot*3+1];
      fo[(ca+slot)*3+2] = scratch[ss][1][bin][slot*3+2];
    }
  }
  if (t < 8) {
    const int ss = t >> 2, bin = t & 3;
    int tot = cl[ss][0][bin] + cl[ss][1][bin]; if (tot > 64) tot = 64;
    const int g = (blockIdx.x*2 + ss)*4 + bin;
    float* fo = ws + OFF_FEAT + g*192;
    if (tot == 0) { fo[0]=p0s[ss][0]; fo[1]=p0s[ss][1]; fo[2]=p0s[ss][2]; tot = 1; }
    ((int*)(ws + OFF_CNT))[g] = tot;
  }
}

// ---------------- kernel 2: SharedMLP + maxpool via bf16 MFMA (R4-verified, static) ----------------
__global__ __launch_bounds__(256) void mlp_kernel(float* __restrict__ ws){
  __shared__ unsigned short h2s[2][64*136];
  __shared__ float w1q[4][256];
  const int t = threadIdx.x;
  const int wave = t >> 6, lane = t & 63;
  const int quad = lane >> 4, l15 = lane & 15;
  const int grp = wave >> 1, nhalf = wave & 1;
  const int g = blockIdx.x*2 + grp;
  for (int i = t; i < 1024; i += 256) w1q[i>>8][i&255] = ws[OFF_W1Q + (i&255)];
  const int V = ((const int*)(ws + OFF_CNT))[g];
  const float* feat = ws + OFF_FEAT + g*192;
  __syncthreads();
  bf16x8 a1[4][2];
  const float* wq = w1q[quad];
#pragma unroll
  for (int mt = 0; mt < 4; ++mt) {
    const int m = mt*16 + l15;
    const float x0 = feat[m*3+0], x1 = feat[m*3+1], x2 = feat[m*3+2];
#pragma unroll
    for (int kt = 0; kt < 2; ++kt) {
      const int c0 = kt*32 + quad*8;
#pragma unroll
      for (int j = 0; j < 8; ++j) {
        const float* w = wq + (c0+j)*4;
        a1[mt][kt][j] = (short)f2bf(fmaxf(w[3] + x0*w[0] + x1*w[1] + x2*w[2], 0.f));
      }
    }
  }
  unsigned short* h2 = h2s[grp];
  const bf16x8* BW2 = (const bf16x8*)(ws + OFF_BW2);
#pragma unroll
  for (int nt4 = 0; nt4 < 4; ++nt4) {
    const int nt = nhalf*4 + nt4;
    const int n = nt*16 + l15;
    const float bias = ws[OFF_B2 + n];
    f32x4 acc[4];
#pragma unroll
    for (int mt = 0; mt < 4; ++mt) acc[mt] = (f32x4){bias, bias, bias, bias};
#pragma unroll
    for (int kt = 0; kt < 2; ++kt) {
      const bf16x8 b = BW2[(nt*2+kt)*64 + lane];
#pragma unroll
      for (int mt = 0; mt < 4; ++mt)
        acc[mt] = __builtin_amdgcn_mfma_f32_16x16x32_bf16(a1[mt][kt], b, acc[mt], 0, 0, 0);
    }
#pragma unroll
    for (int mt = 0; mt < 4; ++mt)
#pragma unroll
      for (int jj = 0; jj < 4; ++jj) {
        const int m = mt*16 + quad*4 + jj;
        h2[m*136 + n] = f2bf(fmaxf(acc[mt][jj], 0.f));
      }
  }
  __syncthreads();
  bf16x8 a2[4][4];
#pragma unroll
  for (int mt = 0; mt < 4; ++mt)
#pragma unroll
    for (int kt = 0; kt < 4; ++kt)
      a2[mt][kt] = *(const bf16x8*)&h2[(mt*16 + l15)*136 + kt*32 + quad*8];
  const bf16x8* BW3 = (const bf16x8*)(ws + OFF_BW3);
  float vpv[8];
#pragma unroll
  for (int nt8 = 0; nt8 < 8; ++nt8) {
    const int nt = nhalf*8 + nt8;
    const int n = nt*16 + l15;
    const float bias = ws[OFF_B3 + n];
    f32x4 acc[4];
#pragma unroll
    for (int mt = 0; mt < 4; ++mt) acc[mt] = (f32x4){bias, bias, bias, bias};
#pragma unroll
    for (int kt = 0; kt < 4; ++kt) {
      const bf16x8 b = BW3[(nt*4+kt)*64 + lane];
#pragma unroll
      for (int mt = 0; mt < 4; ++mt)
        acc[mt] = __builtin_amdgcn_mfma_f32_16x16x32_bf16(a2[mt][kt], b, acc[mt], 0, 0, 0);
    }
    float mx = 0.f;
#pragma unroll
    for (int mt = 0; mt < 4; ++mt)
#pragma unroll
      for (int jj = 0; jj < 4; ++jj) {
        const int row = mt*16 + quad*4 + jj;
        const float v = fmaxf(acc[mt][jj], 0.f);
        mx = (row < V) ? fmaxf(mx, v) : mx;
      }
    mx = fmaxf(mx, __shfl_xor(mx, 16, 64));
    mx = fmaxf(mx, __shfl_xor(mx, 32, 64));
    vpv[nt8] = mx;
  }
  if (quad == 0) {
    float* vp = ws + OFF_VP + g*256 + nhalf*128;
#pragma unroll
    for (int nt8 = 0; nt8 < 8; ++nt8) vp[nt8*16 + l15] = vpv[nt8];
  }
}

// ---------------- kernel 3: heads via bf16 MFMA, fused transpose write ----------------
#define YSTRIDE 264
__global__ __launch_bounds__(256) void heads_kernel(float* __restrict__ ws, void* __restrict__ outv){
  const int isf32 = ((const volatile int*)(ws + OFF_FLAG))[0];
  __shared__ unsigned short y[16*YSTRIDE];
  const int t = threadIdx.x;
  const int wave = t >> 6, lane = t & 63;
  const int quad = lane >> 4, l15 = lane & 15;
  const int r0 = blockIdx.x * 16;
  bf16x8 a[8];
  const float* vp = ws + OFF_VP + (r0 + l15)*256;
#pragma unroll
  for (int kt = 0; kt < 8; ++kt) {
    const float4* v4 = (const float4*)(vp + kt*32 + quad*8);
    float4 u0 = v4[0], u1 = v4[1];
    a[kt][0]=(short)f2bf(u0.x); a[kt][1]=(short)f2bf(u0.y); a[kt][2]=(short)f2bf(u0.z); a[kt][3]=(short)f2bf(u0.w);
    a[kt][4]=(short)f2bf(u1.x); a[kt][5]=(short)f2bf(u1.y); a[kt][6]=(short)f2bf(u1.z); a[kt][7]=(short)f2bf(u1.w);
  }
  const bf16x8* HB1 = (const bf16x8*)(ws + OFF_HB1);
#pragma unroll
  for (int nt4 = 0; nt4 < 4; ++nt4) {
    const int nt = wave*4 + nt4;
    const int n = nt*16 + l15;
    const float bias = ws[OFF_HB1B + n];
    f32x4 acc = (f32x4){bias, bias, bias, bias};
#pragma unroll
    for (int kt = 0; kt < 8; ++kt)
      acc = __builtin_amdgcn_mfma_f32_16x16x32_bf16(a[kt], HB1[(nt*8+kt)*64 + lane], acc, 0, 0, 0);
#pragma unroll
    for (int jj = 0; jj < 4; ++jj)
      y[(quad*4+jj)*YSTRIDE + n] = f2bf(fmaxf(acc[jj], 0.f));
  }
  __syncthreads();
#pragma unroll
  for (int kt = 0; kt < 8; ++kt)
    a[kt] = *(const bf16x8*)&y[l15*YSTRIDE + kt*32 + quad*8];
  __syncthreads();
  const bf16x8* HB2 = (const bf16x8*)(ws + OFF_HB2);
#pragma unroll
  for (int nt4 = 0; nt4 < 4; ++nt4) {
    const int nt = wave*4 + nt4;
    const int n = nt*16 + l15;
    const float bias = ws[OFF_HB2B + n];
    f32x4 acc = (f32x4){bias, bias, bias, bias};
#pragma unroll
    for (int kt = 0; kt < 8; ++kt)
      acc = __builtin_amdgcn_mfma_f32_16x16x32_bf16(a[kt], HB2[(nt*8+kt)*64 + lane], acc, 0, 0, 0);
#pragma unroll
    for (int jj = 0; jj < 4; ++jj)
      y[(quad*4+jj)*YSTRIDE + n] = f2bf(fmaxf(acc[jj], 0.f));
  }
  __syncthreads();
#pragma unroll
  for (int kt = 0; kt < 8; ++kt)
    a[kt] = *(const bf16x8*)&y[l15*YSTRIDE + kt*32 + quad*8];
  const bf16x8* HB3 = (const bf16x8*)(ws + OFF_HB3);
  {
    const int n = wave*16 + l15;
    const float bias = ws[OFF_HB3B + n];
    f32x4 acc = (f32x4){bias, bias, bias, bias};
#pragma unroll
    for (int kt = 0; kt < 8; ++kt)
      acc = __builtin_amdgcn_mfma_f32_16x16x32_bf16(a[kt], HB3[(wave*8+kt)*64 + lane], acc, 0, 0, 0);
    if (n < 48) {
#pragma unroll
      for (int jj = 0; jj < 4; ++jj) {
        const int gr = r0 + quad*4 + jj;
        const int b = gr >> 12, rem = gr & 4095, s = rem >> 2, d = rem & 3;
        const int o = ((b*48 + n)*1024 + s)*4 + d;
        if (isf32) ((float*)outv)[o] = acc[jj];
        else       ((__hip_bfloat16*)outv)[o] = __float2bfloat16(acc[jj]);
      }
    }
  }
}

extern "C" void kernel_launch(void* const* d_in, const int* in_sizes, int n_in,
                              void* d_out, int out_size, void* d_ws, size_t ws_size,
                              hipStream_t stream) {
  float* ws = (float*)d_ws;
  Ptrs P;
  for (int i = 0; i < 25; ++i) P.p[i] = d_in[i];
  detect_kernel<<<1, 256, 0, stream>>>(d_in[5], d_in[7], (int*)(ws + OFF_FLAG));
  prep_kernel<<<(PREP_TOTAL+255)/256, 256, 0, stream>>>(P, ws);
  group_kernel<<<NB*NS/2, 256, 0, stream>>>(ws);
  mlp_kernel<<<NGROUP/2, 256, 0, stream>>>(ws);
  heads_kernel<<<NGROUP/16, 256, 0, stream>>>(ws, d_out);
}

// Round 8
// 210.534 us; speedup vs baseline: 1.6952x; 1.0280x over previous
//
#include <hip/hip_runtime.h>
#include <hip/hip_bf16.h>

// ---------------- problem constants ----------------
#define NB    2
#define NS    1024
#define NPTS  8192
#define NGROUP (NB*NS*4)   // 8192 groups = rows

// ---------------- ws layout (float offsets) ----------------
enum : int {
  OFF_BW2  = 256,      // 8192 bf16: W2 folded, frag order (A- and B-frag maps coincide)
  OFF_W1Q  = 4352,     // 64 x float4 (w0,w1,w2,b) folded L1
  OFF_B2   = 8448,     // 128 f32
  OFF_BW3  = 8576,     // 32768 bf16: W3 folded, B-frag order
  OFF_B3   = 41344,    // 256 f32
  OFF_HB1  = 41600,    // 65536 bf16: combined head L1 (256x256), B-frag order
  OFF_HB1B = 74368,    // 256 f32
  OFF_HB2  = 74624,    // 65536 bf16: combined head L2 (256x256 block-diag)
  OFF_HB2B = 107392,   // 256 f32
  OFF_HB3  = 107648,   // 16384 bf16: combined head L3 (64x256 block-struct)
  OFF_HB3B = 115840,   // 64 f32
  OFF_FEAT = 146688,            // 8192 * 64 * 3
  OFF_VP   = 1719552,           // 8192 * 256 (written by mlp, read by heads)
  // --- overlaid into VP region: live only between prep and mlp ---
  OFF_PCX  = 1719552,           // 16384 f32 (2 batches x 8192)
  OFF_PCY  = 1735936,
  OFF_PCZ  = 1752320,
  OFF_SEED = 1768704,           // 6144 f32
  OFF_ROT  = 1774848,           // 18432 f32
  OFF_FLAG = 3824896,           // 1 int: 0 = bf16 inputs, 1 = fp32 inputs (for heads)
  PREP_TOTAL = 189632 + 6144 + 18432 + 49152,  // = 263360
};

struct Ptrs { const void* p[25]; };

typedef __attribute__((ext_vector_type(8))) short bf16x8;
typedef __attribute__((ext_vector_type(4))) float f32x4;

template<typename T> struct LD;
template<> struct LD<float> {
  static __device__ __forceinline__ float get(const void* p, int i){ return ((const float*)p)[i]; }
};
template<> struct LD<__hip_bfloat16> {
  static __device__ __forceinline__ float get(const void* p, int i){ return __bfloat162float(((const __hip_bfloat16*)p)[i]); }
};

template<typename T>
__device__ __forceinline__ float bnscale(const void* bn, int C, int c){
  float g = LD<T>::get(bn, c);
  float v = LD<T>::get(bn, 3*C + c);
  return g / sqrtf(v + 1e-5f);
}

__device__ __forceinline__ unsigned short f2bf(float v){
  __hip_bfloat16 hb = __float2bfloat16(v);
  return *reinterpret_cast<unsigned short*>(&hb);
}

#if __has_builtin(__builtin_amdgcn_cvt_pk_bf16_f32)
typedef __attribute__((ext_vector_type(2))) __bf16 bf16x2_t;
__device__ __forceinline__ unsigned pk2bf(float a, float b){
  bf16x2_t r = __builtin_amdgcn_cvt_pk_bf16_f32(a, b);
  return *reinterpret_cast<unsigned*>(&r);
}
#else
__device__ __forceinline__ unsigned pk2bf(float a, float b){
  return (unsigned)f2bf(a) | ((unsigned)f2bf(b) << 16);
}
#endif

// ---------------- prep body: fold BN; swizzle weights; fp32 SoA geometry ----------------
template<typename T>
__device__ void prep_body(const Ptrs& in, float* __restrict__ ws, int i){
  if (i < 256) { int c = i>>2, d = i&3; float s = bnscale<T>(in.p[4],64,c);
    float v = (d<3) ? LD<T>::get(in.p[3], c*3+d)*s
                    : LD<T>::get(in.p[4],64+c) - LD<T>::get(in.p[4],2*64+c)*s;
    ws[OFF_W1Q+i] = v; return; }
  i -= 256;
  if (i < 8192) { // BW2: 128x64, KT=2 (used as A-frags: m=channel)
    int j = i&7, f = i>>3, lane = f&63, kn = f>>6, kt = kn&1, nt = kn>>1;
    int n = nt*16 + (lane&15), k = kt*32 + ((lane>>4)<<3) + j;
    float s = bnscale<T>(in.p[6],128,n);
    ((unsigned short*)(ws + OFF_BW2))[i] = f2bf(LD<T>::get(in.p[5], n*64+k)*s); return; }
  i -= 8192;
  if (i < 32768) { // BW3: 256x128, KT=4
    int j = i&7, f = i>>3, lane = f&63, kn = f>>6, kt = kn&3, nt = kn>>2;
    int n = nt*16 + (lane&15), k = kt*32 + ((lane>>4)<<3) + j;
    float s = bnscale<T>(in.p[8],256,n);
    ((unsigned short*)(ws + OFF_BW3))[i] = f2bf(LD<T>::get(in.p[7], n*128+k)*s); return; }
  i -= 32768;
  if (i < 128) { float s = bnscale<T>(in.p[6],128,i);
    ws[OFF_B2+i] = LD<T>::get(in.p[6],128+i) - LD<T>::get(in.p[6],2*128+i)*s; return; }
  i -= 128;
  if (i < 256) { float s = bnscale<T>(in.p[8],256,i);
    ws[OFF_B3+i] = LD<T>::get(in.p[8],256+i) - LD<T>::get(in.p[8],2*256+i)*s; return; }
  i -= 256;
  if (i < 65536) { // HB1: combined 256x256, KT=8
    int j = i&7, f = i>>3, lane = f&63, kn = f>>6, kt = kn&7, nt = kn>>3;
    int n = nt*16 + (lane&15), k = kt*32 + ((lane>>4)<<3) + j;
    float v;
    if (n < 128) v = LD<T>::get(in.p[9],  n*256+k)       * bnscale<T>(in.p[11],128,n);
    else         v = LD<T>::get(in.p[17], (n-128)*256+k) * bnscale<T>(in.p[19],128,n-128);
    ((unsigned short*)(ws + OFF_HB1))[i] = f2bf(v); return; }
  i -= 65536;
  if (i < 256) { int n = i; float v;
    if (n < 128) { float s = bnscale<T>(in.p[11],128,n);
      v = (LD<T>::get(in.p[10],n) - LD<T>::get(in.p[11],2*128+n))*s + LD<T>::get(in.p[11],128+n); }
    else { int m = n-128; float s = bnscale<T>(in.p[19],128,m);
      v = (LD<T>::get(in.p[18],m) - LD<T>::get(in.p[19],2*128+m))*s + LD<T>::get(in.p[19],128+m); }
    ws[OFF_HB1B+n] = v; return; }
  i -= 256;
  if (i < 65536) { // HB2: 256x256 block-diagonal
    int j = i&7, f = i>>3, lane = f&63, kn = f>>6, kt = kn&7, nt = kn>>3;
    int n = nt*16 + (lane&15), k = kt*32 + ((lane>>4)<<3) + j;
    float v = 0.f;
    if (n < 128) { if (k < 128)  v = LD<T>::get(in.p[12], n*128+k)            * bnscale<T>(in.p[14],128,n); }
    else         { if (k >= 128) v = LD<T>::get(in.p[20], (n-128)*128+(k-128)) * bnscale<T>(in.p[22],128,n-128); }
    ((unsigned short*)(ws + OFF_HB2))[i] = f2bf(v); return; }
  i -= 65536;
  if (i < 256) { int n = i; float v;
    if (n < 128) { float s = bnscale<T>(in.p[14],128,n);
      v = (LD<T>::get(in.p[13],n) - LD<T>::get(in.p[14],2*128+n))*s + LD<T>::get(in.p[14],128+n); }
    else { int m = n-128; float s = bnscale<T>(in.p[22],128,m);
      v = (LD<T>::get(in.p[21],m) - LD<T>::get(in.p[22],2*128+m))*s + LD<T>::get(in.p[22],128+m); }
    ws[OFF_HB2B+n] = v; return; }
  i -= 256;
  if (i < 16384) { // HB3: 64x256
    int j = i&7, f = i>>3, lane = f&63, kn = f>>6, kt = kn&7, nt = kn>>3;
    int n = nt*16 + (lane&15), k = kt*32 + ((lane>>4)<<3) + j;
    float v = 0.f;
    if (n < 36)      { if (k < 128)  v = LD<T>::get(in.p[15], n*128+k); }
    else if (n < 48) { if (k >= 128) v = LD<T>::get(in.p[23], (n-36)*128+(k-128)); }
    ((unsigned short*)(ws + OFF_HB3))[i] = f2bf(v); return; }
  i -= 16384;
  if (i < 64) { int n = i; float v = 0.f;
    if (n < 36) v = LD<T>::get(in.p[16], n);
    else if (n < 48) v = LD<T>::get(in.p[24], n-36);
    ws[OFF_HB3B+n] = v; return; }
  i -= 64;
  if (i < 6144)  { ws[OFF_SEED+i] = LD<T>::get(in.p[0], i); return; }
  i -= 6144;
  if (i < 18432) { ws[OFF_ROT+i] = LD<T>::get(in.p[2], i); return; }
  i -= 18432;
  { // pointcloud SoA
    int arr = i >> 14, idx = i & 16383;
    ws[OFF_PCX + arr*16384 + idx] = LD<T>::get(in.p[1], idx*3 + arr); }
}

// ---------------- kernel 0: detect dtype (per-block) + prep ----------------
// True-bf16 finite weights never have exp=0xFF; fp32 halves hit it w.p. 1/256
// per uniform short. 16384 shorts of w3 => P(miss|fp32) ~ e^-32.
__global__ __launch_bounds__(256) void prep_kernel(Ptrs in, float* __restrict__ ws){
  __shared__ int sf;
  const int t = threadIdx.x;
  if (t == 0) sf = 0;
  __syncthreads();
  int loc = 0;
  const uint4* w3r = (const uint4*)in.p[7];
#pragma unroll
  for (int k = 0; k < 8; ++k) {
    uint4 u = w3r[t + k*256];
    loc |= ((u.x & 0x7F80u) == 0x7F80u) | (((u.x>>16) & 0x7F80u) == 0x7F80u);
    loc |= ((u.y & 0x7F80u) == 0x7F80u) | (((u.y>>16) & 0x7F80u) == 0x7F80u);
    loc |= ((u.z & 0x7F80u) == 0x7F80u) | (((u.z>>16) & 0x7F80u) == 0x7F80u);
    loc |= ((u.w & 0x7F80u) == 0x7F80u) | (((u.w>>16) & 0x7F80u) == 0x7F80u);
  }
  if (loc) atomicOr(&sf, 1);
  __syncthreads();
  const int isf32 = sf;
  const int i = blockIdx.x*256 + t;
  if (i == 0) ((int*)(ws + OFF_FLAG))[0] = isf32;   // for heads
  if (i >= PREP_TOTAL) return;
  if (isf32) prep_body<float>(in, ws, i);
  else       prep_body<__hip_bfloat16>(in, ws, i);
}

// ---------------- group: 2 seeds/block, 2 waves/seed, fill-to-64 merge ----------------
// Fill duplicates the first-found point into slots [tot,64) — exactly the
// reference's idx[...,:1] fill — so mlp needs no V masking at all.
__global__ __launch_bounds__(256) void group_kernel(float* __restrict__ ws){
#pragma clang fp contract(off)
  __shared__ float scratch[2][2][4][192];   // [seed][half][bin][slot*3]
  __shared__ int   cl[2][2][4];
  __shared__ float p0s[2][3];
  const int t = threadIdx.x;
  const int wave = t >> 6, lane = t & 63;
  const int s = wave >> 1, half = wave & 1;
  const int seedIdx = blockIdx.x*2 + s;
  const int b = seedIdx >> 10;
  const float sx = ws[OFF_SEED + seedIdx*3+0];
  const float sy = ws[OFF_SEED + seedIdx*3+1];
  const float sz = ws[OFF_SEED + seedIdx*3+2];
  const float r00=ws[OFF_ROT+seedIdx*9+0], r01=ws[OFF_ROT+seedIdx*9+1], r02=ws[OFF_ROT+seedIdx*9+2];
  const float r10=ws[OFF_ROT+seedIdx*9+3], r11=ws[OFF_ROT+seedIdx*9+4], r12=ws[OFF_ROT+seedIdx*9+5];
  const float r20=ws[OFF_ROT+seedIdx*9+6], r21=ws[OFF_ROT+seedIdx*9+7], r22=ws[OFF_ROT+seedIdx*9+8];
  const float* px = ws + OFF_PCX + b*8192;
  const float* py = ws + OFF_PCY + b*8192;
  const float* pz = ws + OFF_PCZ + b*8192;
  if (half == 0 && lane == 0) {
    float e0 = px[0] - sx, e1 = py[0] - sy, e2 = pz[0] - sz;
    p0s[s][0] = e0*r00 + e1*r10 + e2*r20;
    p0s[s][1] = e0*r01 + e1*r11 + e2*r21;
    p0s[s][2] = e0*r02 + e1*r12 + e2*r22;
  }
  float* s0 = scratch[s][half][0];
  float* s1 = scratch[s][half][1];
  float* s2 = scratch[s][half][2];
  float* s3 = scratch[s][half][3];
  int c0n=0, c1n=0, c2n=0, c3n=0;
  const int basept = half*4096;
  const unsigned long long pm = (1ull << lane) - 1ull;

  auto scan = [&](float x, float y, float z){
    float e0 = x - sx, e1 = y - sy, e2 = z - sz;
    float rx = e0*r00 + e1*r10 + e2*r20;
    float ry = e0*r01 + e1*r11 + e2*r21;
    float rz = e0*r02 + e1*r12 + e2*r22;
    float r2 = ry*ry + rz*rz;
    const bool mb = (rx > -0.2f) && (r2 < 0.09f);
    { bool m = mb && (rx < 0.1f); unsigned long long bal = __ballot(m);
      if (bal) { int slot = c0n + __popcll(bal & pm);
        if (m && slot < 64) { s0[slot*3]=rx; s0[slot*3+1]=ry; s0[slot*3+2]=rz; }
        c0n += __popcll(bal); } }
    { bool m = mb && (rx < 0.2f); unsigned long long bal = __ballot(m);
      if (bal) { int slot = c1n + __popcll(bal & pm);
        if (m && slot < 64) { s1[slot*3]=rx; s1[slot*3+1]=ry; s1[slot*3+2]=rz; }
        c1n += __popcll(bal); } }
    { bool m = mb && (rx < 0.3f); unsigned long long bal = __ballot(m);
      if (bal) { int slot = c2n + __popcll(bal & pm);
        if (m && slot < 64) { s2[slot*3]=rx; s2[slot*3+1]=ry; s2[slot*3+2]=rz; }
        c2n += __popcll(bal); } }
    { bool m = mb && (rx < 0.4f); unsigned long long bal = __ballot(m);
      if (bal) { int slot = c3n + __popcll(bal & pm);
        if (m && slot < 64) { s3[slot*3]=rx; s3[slot*3+1]=ry; s3[slot*3+2]=rz; }
        c3n += __popcll(bal); } }
  };

  for (int c = 0; c < 64; c += 2) {
    const int i0 = basept + c*64 + lane;
    float xA = px[i0],    yA = py[i0],    zA = pz[i0];
    float xB = px[i0+64], yB = py[i0+64], zB = pz[i0+64];
    scan(xA, yA, zA);
    scan(xB, yB, zB);
  }
  if (lane == 0) { cl[s][half][0]=c0n; cl[s][half][1]=c1n; cl[s][half][2]=c2n; cl[s][half][3]=c3n; }
  __syncthreads();
  // merge + fill: A slots [0,ca), B slots [ca, ca+cb), fill the rest
  for (int idx = t; idx < 512; idx += 256) {
    const int ss = idx >> 8, bin = (idx >> 6) & 3, slot = idx & 63;
    int ca = cl[ss][0][bin]; if (ca > 64) ca = 64;
    int cb = cl[ss][1][bin];
    const float* A = scratch[ss][0][bin];
    const float* B = scratch[ss][1][bin];
    float fx, fy, fz;
    if (slot < ca)              { fx=A[slot*3]; fy=A[slot*3+1]; fz=A[slot*3+2]; }
    else if (slot - ca < cb)    { int q = slot-ca; fx=B[q*3]; fy=B[q*3+1]; fz=B[q*3+2]; }
    else if (ca > 0)            { fx=A[0]; fy=A[1]; fz=A[2]; }
    else if (cb > 0)            { fx=B[0]; fy=B[1]; fz=B[2]; }
    else                        { fx=p0s[ss][0]; fy=p0s[ss][1]; fz=p0s[ss][2]; }
    const int g = (blockIdx.x*2 + ss)*4 + bin;
    float* fo = ws + OFF_FEAT + g*192;
    fo[slot*3+0]=fx; fo[slot*3+1]=fy; fo[slot*3+2]=fz;
  }
}

// ---------------- kernel 2: SharedMLP + maxpool, role-swapped L2 ----------------
// L2: A = W2 (channels=M, BW2 frags double as A-frags), B = h1 built in B-layout.
// C = channels x samples -> lane's 4 values are channel-adjacent -> one b64
// packed LDS store into h2[sample][channel]. L3 unchanged (A = h2, b128 reads).
// No V masking anywhere: group pre-filled slots [V,64) with the fill point.
__global__ __launch_bounds__(256) void mlp_kernel(float* __restrict__ ws){
  __shared__ unsigned short h2s[2][64*136];
  __shared__ float w1q[4][256];
  const int t = threadIdx.x;
  const int wave = t >> 6, lane = t & 63;
  const int quad = lane >> 4, l15 = lane & 15;
  const int grp = wave >> 1, nhalf = wave & 1;
  const int g = blockIdx.x*2 + grp;
  for (int i = t; i < 1024; i += 256) w1q[i>>8][i&255] = ws[OFF_W1Q + (i&255)];
  const float* feat = ws + OFF_FEAT + g*192;
  __syncthreads();
  // ---- L1 into B-frags: lane -> (n = Nt*16+l15 sample, k = kt*32+quad*8+j channel) ----
  bf16x8 b1[4][2];
  const float* wq = w1q[quad];
#pragma unroll
  for (int Nt = 0; Nt < 4; ++Nt) {
    const int sm = Nt*16 + l15;
    const float x0 = feat[sm*3+0], x1 = feat[sm*3+1], x2 = feat[sm*3+2];
#pragma unroll
    for (int kt = 0; kt < 2; ++kt) {
      const int c0 = kt*32 + quad*8;
#pragma unroll
      for (int j = 0; j < 8; ++j) {
        const float* w = wq + (c0+j)*4;
        b1[Nt][kt][j] = (short)f2bf(fmaxf(w[3] + x0*w[0] + x1*w[1] + x2*w[2], 0.f));
      }
    }
  }
  // ---- L2: 128x64x64, wave does Mt = nhalf*4 + mt4 (channel tiles) ----
  unsigned short* h2 = h2s[grp];
  const bf16x8* BW2 = (const bf16x8*)(ws + OFF_BW2);
#pragma unroll
  for (int mt4 = 0; mt4 < 4; ++mt4) {
    const int Mt = nhalf*4 + mt4;
    const f32x4 bias4 = *(const f32x4*)(ws + OFF_B2 + Mt*16 + quad*4);
    f32x4 acc[4];
#pragma unroll
    for (int Nt = 0; Nt < 4; ++Nt) acc[Nt] = bias4;
#pragma unroll
    for (int kt = 0; kt < 2; ++kt) {
      const bf16x8 aw = BW2[(Mt*2+kt)*64 + lane];
#pragma unroll
      for (int Nt = 0; Nt < 4; ++Nt)
        acc[Nt] = __builtin_amdgcn_mfma_f32_16x16x32_bf16(aw, b1[Nt][kt], acc[Nt], 0, 0, 0);
    }
#pragma unroll
    for (int Nt = 0; Nt < 4; ++Nt) {
      const unsigned lo = pk2bf(fmaxf(acc[Nt][0],0.f), fmaxf(acc[Nt][1],0.f));
      const unsigned hi = pk2bf(fmaxf(acc[Nt][2],0.f), fmaxf(acc[Nt][3],0.f));
      uint2* dst = (uint2*)&h2[(Nt*16 + l15)*136 + Mt*16 + quad*4];
      *dst = make_uint2(lo, hi);
    }
  }
  __syncthreads();
  // ---- L3: 64x256x128 + fused relu/maxpool (no masking) ----
  bf16x8 a2[4][4];
#pragma unroll
  for (int mt = 0; mt < 4; ++mt)
#pragma unroll
    for (int kt = 0; kt < 4; ++kt)
      a2[mt][kt] = *(const bf16x8*)&h2[(mt*16 + l15)*136 + kt*32 + quad*8];
  const bf16x8* BW3 = (const bf16x8*)(ws + OFF_BW3);
  float vpv[8];
#pragma unroll
  for (int nt8 = 0; nt8 < 8; ++nt8) {
    const int nt = nhalf*8 + nt8;
    const int n = nt*16 + l15;
    const float bias = ws[OFF_B3 + n];
    f32x4 acc[4];
#pragma unroll
    for (int mt = 0; mt < 4; ++mt) acc[mt] = (f32x4){bias, bias, bias, bias};
#pragma unroll
    for (int kt = 0; kt < 4; ++kt) {
      const bf16x8 b = BW3[(nt*4+kt)*64 + lane];
#pragma unroll
      for (int mt = 0; mt < 4; ++mt)
        acc[mt] = __builtin_amdgcn_mfma_f32_16x16x32_bf16(a2[mt][kt], b, acc[mt], 0, 0, 0);
    }
    float mx = 0.f;   // relu >= 0 so 0 is a safe identity
#pragma unroll
    for (int mt = 0; mt < 4; ++mt) {
      mx = fmaxf(mx, fmaxf(fmaxf(acc[mt][0], acc[mt][1]), fmaxf(acc[mt][2], acc[mt][3])));
    }
    mx = fmaxf(mx, 0.f);
    mx = fmaxf(mx, __shfl_xor(mx, 16, 64));
    mx = fmaxf(mx, __shfl_xor(mx, 32, 64));
    vpv[nt8] = mx;
  }
  if (quad == 0) {
    float* vp = ws + OFF_VP + g*256 + nhalf*128;
#pragma unroll
    for (int nt8 = 0; nt8 < 8; ++nt8) vp[nt8*16 + l15] = vpv[nt8];
  }
}

// ---------------- kernel 3: heads via bf16 MFMA, fused transpose write ----------------
#define YSTRIDE 264
__global__ __launch_bounds__(256) void heads_kernel(float* __restrict__ ws, void* __restrict__ outv){
  const int isf32 = ((const volatile int*)(ws + OFF_FLAG))[0];
  __shared__ unsigned short y[16*YSTRIDE];
  const int t = threadIdx.x;
  const int wave = t >> 6, lane = t & 63;
  const int quad = lane >> 4, l15 = lane & 15;
  const int r0 = blockIdx.x * 16;
  bf16x8 a[8];
  const float* vp = ws + OFF_VP + (r0 + l15)*256;
#pragma unroll
  for (int kt = 0; kt < 8; ++kt) {
    const float4* v4 = (const float4*)(vp + kt*32 + quad*8);
    float4 u0 = v4[0], u1 = v4[1];
    a[kt][0]=(short)f2bf(u0.x); a[kt][1]=(short)f2bf(u0.y); a[kt][2]=(short)f2bf(u0.z); a[kt][3]=(short)f2bf(u0.w);
    a[kt][4]=(short)f2bf(u1.x); a[kt][5]=(short)f2bf(u1.y); a[kt][6]=(short)f2bf(u1.z); a[kt][7]=(short)f2bf(u1.w);
  }
  const bf16x8* HB1 = (const bf16x8*)(ws + OFF_HB1);
#pragma unroll
  for (int nt4 = 0; nt4 < 4; ++nt4) {
    const int nt = wave*4 + nt4;
    const int n = nt*16 + l15;
    const float bias = ws[OFF_HB1B + n];
    f32x4 acc = (f32x4){bias, bias, bias, bias};
#pragma unroll
    for (int kt = 0; kt < 8; ++kt)
      acc = __builtin_amdgcn_mfma_f32_16x16x32_bf16(a[kt], HB1[(nt*8+kt)*64 + lane], acc, 0, 0, 0);
#pragma unroll
    for (int jj = 0; jj < 4; ++jj)
      y[(quad*4+jj)*YSTRIDE + n] = f2bf(fmaxf(acc[jj], 0.f));
  }
  __syncthreads();
#pragma unroll
  for (int kt = 0; kt < 8; ++kt)
    a[kt] = *(const bf16x8*)&y[l15*YSTRIDE + kt*32 + quad*8];
  __syncthreads();
  const bf16x8* HB2 = (const bf16x8*)(ws + OFF_HB2);
#pragma unroll
  for (int nt4 = 0; nt4 < 4; ++nt4) {
    const int nt = wave*4 + nt4;
    const int n = nt*16 + l15;
    const float bias = ws[OFF_HB2B + n];
    f32x4 acc = (f32x4){bias, bias, bias, bias};
#pragma unroll
    for (int kt = 0; kt < 8; ++kt)
      acc = __builtin_amdgcn_mfma_f32_16x16x32_bf16(a[kt], HB2[(nt*8+kt)*64 + lane], acc, 0, 0, 0);
#pragma unroll
    for (int jj = 0; jj < 4; ++jj)
      y[(quad*4+jj)*YSTRIDE + n] = f2bf(fmaxf(acc[jj], 0.f));
  }
  __syncthreads();
#pragma unroll
  for (int kt = 0; kt < 8; ++kt)
    a[kt] = *(const bf16x8*)&y[l15*YSTRIDE + kt*32 + quad*8];
  const bf16x8* HB3 = (const bf16x8*)(ws + OFF_HB3);
  {
    const int n = wave*16 + l15;
    const float bias = ws[OFF_HB3B + n];
    f32x4 acc = (f32x4){bias, bias, bias, bias};
#pragma unroll
    for (int kt = 0; kt < 8; ++kt)
      acc = __builtin_amdgcn_mfma_f32_16x16x32_bf16(a[kt], HB3[(wave*8+kt)*64 + lane], acc, 0, 0, 0);
    if (n < 48) {
#pragma unroll
      for (int jj = 0; jj < 4; ++jj) {
        const int gr = r0 + quad*4 + jj;
        const int b = gr >> 12, rem = gr & 4095, s = rem >> 2, d = rem & 3;
        const int o = ((b*48 + n)*1024 + s)*4 + d;
        if (isf32) ((float*)outv)[o] = acc[jj];
        else       ((__hip_bfloat16*)outv)[o] = __float2bfloat16(acc[jj]);
      }
    }
  }
}

extern "C" void kernel_launch(void* const* d_in, const int* in_sizes, int n_in,
                              void* d_out, int out_size, void* d_ws, size_t ws_size,
                              hipStream_t stream) {
  float* ws = (float*)d_ws;
  Ptrs P;
  for (int i = 0; i < 25; ++i) P.p[i] = d_in[i];
  prep_kernel<<<(PREP_TOTAL+255)/256, 256, 0, stream>>>(P, ws);
  group_kernel<<<NB*NS/2, 256, 0, stream>>>(ws);
  mlp_kernel<<<NGROUP/2, 256, 0, stream>>>(ws);
  heads_kernel<<<NGROUP/16, 256, 0, stream>>>(ws, d_out);
}

// Round 9
// 204.903 us; speedup vs baseline: 1.7418x; 1.0275x over previous
//
#include <hip/hip_runtime.h>
#include <hip/hip_bf16.h>

// ---------------- problem constants ----------------
#define NB    2
#define NS    1024
#define NPTS  8192
#define NGROUP (NB*NS*4)   // 8192 groups = rows

// ---------------- ws layout (float offsets) ----------------
enum : int {
  OFF_BW2  = 256,      // 8192 bf16: W2 folded, frag order (A- and B-frag maps coincide)
  OFF_W1Q  = 4352,     // 64 x float4 (w0,w1,w2,b) folded L1
  OFF_B2   = 8448,     // 128 f32
  OFF_BW3  = 8576,     // 32768 bf16: W3 folded, B-frag order
  OFF_B3   = 41344,    // 256 f32
  OFF_HB1  = 41600,    // 65536 bf16: combined head L1 (256x256), B-frag order
  OFF_HB1B = 74368,    // 256 f32
  OFF_HB2  = 74624,    // 65536 bf16: combined head L2 (256x256 block-diag)
  OFF_HB2B = 107392,   // 256 f32
  OFF_HB3  = 107648,   // 16384 bf16: combined head L3 (64x256 block-struct)
  OFF_HB3B = 115840,   // 64 f32
  OFF_FEAT = 146688,            // 8192 * 64 * 3
  OFF_VP   = 1719552,           // 8192 * 256 (written by mlp, read by heads)
  // --- overlaid into VP region: live only between prep and mlp ---
  OFF_PCX  = 1719552,           // 16384 f32 (2 batches x 8192)
  OFF_PCY  = 1735936,
  OFF_PCZ  = 1752320,
  OFF_SEED = 1768704,           // 6144 f32
  OFF_ROT  = 1774848,           // 18432 f32
  OFF_FLAG = 3824896,           // 1 int: 0 = bf16 inputs, 1 = fp32 inputs (for heads)
  PREP_TOTAL = 189632 + 6144 + 18432 + 49152,  // = 263360
};

struct Ptrs { const void* p[25]; };

typedef __attribute__((ext_vector_type(8))) short bf16x8;
typedef __attribute__((ext_vector_type(4))) float f32x4;
typedef __attribute__((ext_vector_type(4))) unsigned u32x4;

template<typename T> struct LD;
template<> struct LD<float> {
  static __device__ __forceinline__ float get(const void* p, int i){ return ((const float*)p)[i]; }
};
template<> struct LD<__hip_bfloat16> {
  static __device__ __forceinline__ float get(const void* p, int i){ return __bfloat162float(((const __hip_bfloat16*)p)[i]); }
};

template<typename T>
__device__ __forceinline__ float bnscale(const void* bn, int C, int c){
  float g = LD<T>::get(bn, c);
  float v = LD<T>::get(bn, 3*C + c);
  return g / sqrtf(v + 1e-5f);
}

__device__ __forceinline__ unsigned short f2bf(float v){
  __hip_bfloat16 hb = __float2bfloat16(v);
  return *reinterpret_cast<unsigned short*>(&hb);
}

#if __has_builtin(__builtin_amdgcn_cvt_pk_bf16_f32)
typedef __attribute__((ext_vector_type(2))) __bf16 bf16x2_t;
__device__ __forceinline__ unsigned pk2bf(float a, float b){
  bf16x2_t r = __builtin_amdgcn_cvt_pk_bf16_f32(a, b);
  return *reinterpret_cast<unsigned*>(&r);
}
#else
__device__ __forceinline__ unsigned pk2bf(float a, float b){
  return (unsigned)f2bf(a) | ((unsigned)f2bf(b) << 16);
}
#endif

// ---------------- prep body: fold BN; swizzle weights; fp32 SoA geometry ----------------
template<typename T>
__device__ void prep_body(const Ptrs& in, float* __restrict__ ws, int i){
  if (i < 256) { int c = i>>2, d = i&3; float s = bnscale<T>(in.p[4],64,c);
    float v = (d<3) ? LD<T>::get(in.p[3], c*3+d)*s
                    : LD<T>::get(in.p[4],64+c) - LD<T>::get(in.p[4],2*64+c)*s;
    ws[OFF_W1Q+i] = v; return; }
  i -= 256;
  if (i < 8192) { // BW2: 128x64, KT=2 (used as A-frags: m=channel)
    int j = i&7, f = i>>3, lane = f&63, kn = f>>6, kt = kn&1, nt = kn>>1;
    int n = nt*16 + (lane&15), k = kt*32 + ((lane>>4)<<3) + j;
    float s = bnscale<T>(in.p[6],128,n);
    ((unsigned short*)(ws + OFF_BW2))[i] = f2bf(LD<T>::get(in.p[5], n*64+k)*s); return; }
  i -= 8192;
  if (i < 32768) { // BW3: 256x128, KT=4
    int j = i&7, f = i>>3, lane = f&63, kn = f>>6, kt = kn&3, nt = kn>>2;
    int n = nt*16 + (lane&15), k = kt*32 + ((lane>>4)<<3) + j;
    float s = bnscale<T>(in.p[8],256,n);
    ((unsigned short*)(ws + OFF_BW3))[i] = f2bf(LD<T>::get(in.p[7], n*128+k)*s); return; }
  i -= 32768;
  if (i < 128) { float s = bnscale<T>(in.p[6],128,i);
    ws[OFF_B2+i] = LD<T>::get(in.p[6],128+i) - LD<T>::get(in.p[6],2*128+i)*s; return; }
  i -= 128;
  if (i < 256) { float s = bnscale<T>(in.p[8],256,i);
    ws[OFF_B3+i] = LD<T>::get(in.p[8],256+i) - LD<T>::get(in.p[8],2*256+i)*s; return; }
  i -= 256;
  if (i < 65536) { // HB1: combined 256x256, KT=8
    int j = i&7, f = i>>3, lane = f&63, kn = f>>6, kt = kn&7, nt = kn>>3;
    int n = nt*16 + (lane&15), k = kt*32 + ((lane>>4)<<3) + j;
    float v;
    if (n < 128) v = LD<T>::get(in.p[9],  n*256+k)       * bnscale<T>(in.p[11],128,n);
    else         v = LD<T>::get(in.p[17], (n-128)*256+k) * bnscale<T>(in.p[19],128,n-128);
    ((unsigned short*)(ws + OFF_HB1))[i] = f2bf(v); return; }
  i -= 65536;
  if (i < 256) { int n = i; float v;
    if (n < 128) { float s = bnscale<T>(in.p[11],128,n);
      v = (LD<T>::get(in.p[10],n) - LD<T>::get(in.p[11],2*128+n))*s + LD<T>::get(in.p[11],128+n); }
    else { int m = n-128; float s = bnscale<T>(in.p[19],128,m);
      v = (LD<T>::get(in.p[18],m) - LD<T>::get(in.p[19],2*128+m))*s + LD<T>::get(in.p[19],128+m); }
    ws[OFF_HB1B+n] = v; return; }
  i -= 256;
  if (i < 65536) { // HB2: 256x256 block-diagonal
    int j = i&7, f = i>>3, lane = f&63, kn = f>>6, kt = kn&7, nt = kn>>3;
    int n = nt*16 + (lane&15), k = kt*32 + ((lane>>4)<<3) + j;
    float v = 0.f;
    if (n < 128) { if (k < 128)  v = LD<T>::get(in.p[12], n*128+k)            * bnscale<T>(in.p[14],128,n); }
    else         { if (k >= 128) v = LD<T>::get(in.p[20], (n-128)*128+(k-128)) * bnscale<T>(in.p[22],128,n-128); }
    ((unsigned short*)(ws + OFF_HB2))[i] = f2bf(v); return; }
  i -= 65536;
  if (i < 256) { int n = i; float v;
    if (n < 128) { float s = bnscale<T>(in.p[14],128,n);
      v = (LD<T>::get(in.p[13],n) - LD<T>::get(in.p[14],2*128+n))*s + LD<T>::get(in.p[14],128+n); }
    else { int m = n-128; float s = bnscale<T>(in.p[22],128,m);
      v = (LD<T>::get(in.p[21],m) - LD<T>::get(in.p[22],2*128+m))*s + LD<T>::get(in.p[22],128+m); }
    ws[OFF_HB2B+n] = v; return; }
  i -= 256;
  if (i < 16384) { // HB3: 64x256
    int j = i&7, f = i>>3, lane = f&63, kn = f>>6, kt = kn&7, nt = kn>>3;
    int n = nt*16 + (lane&15), k = kt*32 + ((lane>>4)<<3) + j;
    float v = 0.f;
    if (n < 36)      { if (k < 128)  v = LD<T>::get(in.p[15], n*128+k); }
    else if (n < 48) { if (k >= 128) v = LD<T>::get(in.p[23], (n-36)*128+(k-128)); }
    ((unsigned short*)(ws + OFF_HB3))[i] = f2bf(v); return; }
  i -= 16384;
  if (i < 64) { int n = i; float v = 0.f;
    if (n < 36) v = LD<T>::get(in.p[16], n);
    else if (n < 48) v = LD<T>::get(in.p[24], n-36);
    ws[OFF_HB3B+n] = v; return; }
  i -= 64;
  if (i < 6144)  { ws[OFF_SEED+i] = LD<T>::get(in.p[0], i); return; }
  i -= 6144;
  if (i < 18432) { ws[OFF_ROT+i] = LD<T>::get(in.p[2], i); return; }
  i -= 18432;
  { // pointcloud SoA
    int arr = i >> 14, idx = i & 16383;
    ws[OFF_PCX + arr*16384 + idx] = LD<T>::get(in.p[1], idx*3 + arr); }
}

// ---------------- kernel 0: detect dtype (per-block) + prep ----------------
__global__ __launch_bounds__(256) void prep_kernel(Ptrs in, float* __restrict__ ws){
  __shared__ int sf;
  const int t = threadIdx.x;
  if (t == 0) sf = 0;
  __syncthreads();
  int loc = 0;
  const uint4* w3r = (const uint4*)in.p[7];
#pragma unroll
  for (int k = 0; k < 8; ++k) {
    uint4 u = w3r[t + k*256];
    loc |= ((u.x & 0x7F80u) == 0x7F80u) | (((u.x>>16) & 0x7F80u) == 0x7F80u);
    loc |= ((u.y & 0x7F80u) == 0x7F80u) | (((u.y>>16) & 0x7F80u) == 0x7F80u);
    loc |= ((u.z & 0x7F80u) == 0x7F80u) | (((u.z>>16) & 0x7F80u) == 0x7F80u);
    loc |= ((u.w & 0x7F80u) == 0x7F80u) | (((u.w>>16) & 0x7F80u) == 0x7F80u);
  }
  if (loc) atomicOr(&sf, 1);
  __syncthreads();
  const int isf32 = sf;
  const int i = blockIdx.x*256 + t;
  if (i == 0) ((int*)(ws + OFF_FLAG))[0] = isf32;   // for heads
  if (i >= PREP_TOTAL) return;
  if (isf32) prep_body<float>(in, ws, i);
  else       prep_body<__hip_bfloat16>(in, ws, i);
}

// ---------------- group: 2 seeds/block, 2 waves/seed, fill-to-64 merge ----------------
__global__ __launch_bounds__(256) void group_kernel(float* __restrict__ ws){
#pragma clang fp contract(off)
  __shared__ float scratch[2][2][4][192];   // [seed][half][bin][slot*3]
  __shared__ int   cl[2][2][4];
  __shared__ float p0s[2][3];
  const int t = threadIdx.x;
  const int wave = t >> 6, lane = t & 63;
  const int s = wave >> 1, half = wave & 1;
  const int seedIdx = blockIdx.x*2 + s;
  const int b = seedIdx >> 10;
  const float sx = ws[OFF_SEED + seedIdx*3+0];
  const float sy = ws[OFF_SEED + seedIdx*3+1];
  const float sz = ws[OFF_SEED + seedIdx*3+2];
  const float r00=ws[OFF_ROT+seedIdx*9+0], r01=ws[OFF_ROT+seedIdx*9+1], r02=ws[OFF_ROT+seedIdx*9+2];
  const float r10=ws[OFF_ROT+seedIdx*9+3], r11=ws[OFF_ROT+seedIdx*9+4], r12=ws[OFF_ROT+seedIdx*9+5];
  const float r20=ws[OFF_ROT+seedIdx*9+6], r21=ws[OFF_ROT+seedIdx*9+7], r22=ws[OFF_ROT+seedIdx*9+8];
  const float* px = ws + OFF_PCX + b*8192;
  const float* py = ws + OFF_PCY + b*8192;
  const float* pz = ws + OFF_PCZ + b*8192;
  if (half == 0 && lane == 0) {
    float e0 = px[0] - sx, e1 = py[0] - sy, e2 = pz[0] - sz;
    p0s[s][0] = e0*r00 + e1*r10 + e2*r20;
    p0s[s][1] = e0*r01 + e1*r11 + e2*r21;
    p0s[s][2] = e0*r02 + e1*r12 + e2*r22;
  }
  float* s0 = scratch[s][half][0];
  float* s1 = scratch[s][half][1];
  float* s2 = scratch[s][half][2];
  float* s3 = scratch[s][half][3];
  int c0n=0, c1n=0, c2n=0, c3n=0;
  const int basept = half*4096;
  const unsigned long long pm = (1ull << lane) - 1ull;

  auto scan = [&](float x, float y, float z){
    float e0 = x - sx, e1 = y - sy, e2 = z - sz;
    float rx = e0*r00 + e1*r10 + e2*r20;
    float ry = e0*r01 + e1*r11 + e2*r21;
    float rz = e0*r02 + e1*r12 + e2*r22;
    float r2 = ry*ry + rz*rz;
    const bool mb = (rx > -0.2f) && (r2 < 0.09f);
    { bool m = mb && (rx < 0.1f); unsigned long long bal = __ballot(m);
      if (bal) { int slot = c0n + __popcll(bal & pm);
        if (m && slot < 64) { s0[slot*3]=rx; s0[slot*3+1]=ry; s0[slot*3+2]=rz; }
        c0n += __popcll(bal); } }
    { bool m = mb && (rx < 0.2f); unsigned long long bal = __ballot(m);
      if (bal) { int slot = c1n + __popcll(bal & pm);
        if (m && slot < 64) { s1[slot*3]=rx; s1[slot*3+1]=ry; s1[slot*3+2]=rz; }
        c1n += __popcll(bal); } }
    { bool m = mb && (rx < 0.3f); unsigned long long bal = __ballot(m);
      if (bal) { int slot = c2n + __popcll(bal & pm);
        if (m && slot < 64) { s2[slot*3]=rx; s2[slot*3+1]=ry; s2[slot*3+2]=rz; }
        c2n += __popcll(bal); } }
    { bool m = mb && (rx < 0.4f); unsigned long long bal = __ballot(m);
      if (bal) { int slot = c3n + __popcll(bal & pm);
        if (m && slot < 64) { s3[slot*3]=rx; s3[slot*3+1]=ry; s3[slot*3+2]=rz; }
        c3n += __popcll(bal); } }
  };

  for (int c = 0; c < 64; c += 2) {
    const int i0 = basept + c*64 + lane;
    float xA = px[i0],    yA = py[i0],    zA = pz[i0];
    float xB = px[i0+64], yB = py[i0+64], zB = pz[i0+64];
    scan(xA, yA, zA);
    scan(xB, yB, zB);
  }
  if (lane == 0) { cl[s][half][0]=c0n; cl[s][half][1]=c1n; cl[s][half][2]=c2n; cl[s][half][3]=c3n; }
  __syncthreads();
  // merge + fill: A slots [0,ca), B slots [ca, ca+cb), fill the rest
  for (int idx = t; idx < 512; idx += 256) {
    const int ss = idx >> 8, bin = (idx >> 6) & 3, slot = idx & 63;
    int ca = cl[ss][0][bin]; if (ca > 64) ca = 64;
    int cb = cl[ss][1][bin];
    const float* A = scratch[ss][0][bin];
    const float* B = scratch[ss][1][bin];
    float fx, fy, fz;
    if (slot < ca)              { fx=A[slot*3]; fy=A[slot*3+1]; fz=A[slot*3+2]; }
    else if (slot - ca < cb)    { int q = slot-ca; fx=B[q*3]; fy=B[q*3+1]; fz=B[q*3+2]; }
    else if (ca > 0)            { fx=A[0]; fy=A[1]; fz=A[2]; }
    else if (cb > 0)            { fx=B[0]; fy=B[1]; fz=B[2]; }
    else                        { fx=p0s[ss][0]; fy=p0s[ss][1]; fz=p0s[ss][2]; }
    const int g = (blockIdx.x*2 + ss)*4 + bin;
    float* fo = ws + OFF_FEAT + g*192;
    fo[slot*3+0]=fx; fo[slot*3+1]=fy; fo[slot*3+2]=fz;
  }
}

// ---------------- kernel 2: SharedMLP + maxpool, role-swapped L2, hoisted L1 ----------------
// L1 restructured: kt-outer loop hoists the quad's 8 channel-weights into 32
// VGPRs once and reuses them across all 4 Nt samples (ds_reads 64 -> 16/wave);
// h1 packed with pk2bf pairs. Math order identical to R8 (same FMA order, RNE
// conversions) => bit-identical results.
__global__ __launch_bounds__(256) void mlp_kernel(float* __restrict__ ws){
  __shared__ unsigned short h2s[2][64*136];
  __shared__ float w1q[4][256];
  const int t = threadIdx.x;
  const int wave = t >> 6, lane = t & 63;
  const int quad = lane >> 4, l15 = lane & 15;
  const int grp = wave >> 1, nhalf = wave & 1;
  const int g = blockIdx.x*2 + grp;
  for (int i = t; i < 1024; i += 256) w1q[i>>8][i&255] = ws[OFF_W1Q + (i&255)];
  const float* feat = ws + OFF_FEAT + g*192;
  __syncthreads();
  // ---- L1 into B-frags: lane -> (n = Nt*16+l15 sample, k = kt*32+quad*8+j channel) ----
  float fx[4], fy[4], fz[4];
#pragma unroll
  for (int Nt = 0; Nt < 4; ++Nt) {
    const int sm = Nt*16 + l15;
    fx[Nt] = feat[sm*3+0]; fy[Nt] = feat[sm*3+1]; fz[Nt] = feat[sm*3+2];
  }
  bf16x8 b1[4][2];
  const float* wq = w1q[quad];
#pragma unroll
  for (int kt = 0; kt < 2; ++kt) {
    f32x4 w[8];
#pragma unroll
    for (int j = 0; j < 8; ++j) w[j] = *(const f32x4*)(wq + (kt*32 + quad*8 + j)*4);
#pragma unroll
    for (int Nt = 0; Nt < 4; ++Nt) {
      const float x0 = fx[Nt], x1 = fy[Nt], x2 = fz[Nt];
      u32x4 p;
#pragma unroll
      for (int jp = 0; jp < 4; ++jp) {
        const f32x4 wa = w[2*jp], wb = w[2*jp+1];
        const float v0 = fmaxf(wa[3] + x0*wa[0] + x1*wa[1] + x2*wa[2], 0.f);
        const float v1 = fmaxf(wb[3] + x0*wb[0] + x1*wb[1] + x2*wb[2], 0.f);
        p[jp] = pk2bf(v0, v1);
      }
      b1[Nt][kt] = __builtin_bit_cast(bf16x8, p);
    }
  }
  // ---- L2: 128x64x64, wave does Mt = nhalf*4 + mt4 (channel tiles) ----
  unsigned short* h2 = h2s[grp];
  const bf16x8* BW2 = (const bf16x8*)(ws + OFF_BW2);
#pragma unroll
  for (int mt4 = 0; mt4 < 4; ++mt4) {
    const int Mt = nhalf*4 + mt4;
    const f32x4 bias4 = *(const f32x4*)(ws + OFF_B2 + Mt*16 + quad*4);
    f32x4 acc[4];
#pragma unroll
    for (int Nt = 0; Nt < 4; ++Nt) acc[Nt] = bias4;
#pragma unroll
    for (int kt = 0; kt < 2; ++kt) {
      const bf16x8 aw = BW2[(Mt*2+kt)*64 + lane];
#pragma unroll
      for (int Nt = 0; Nt < 4; ++Nt)
        acc[Nt] = __builtin_amdgcn_mfma_f32_16x16x32_bf16(aw, b1[Nt][kt], acc[Nt], 0, 0, 0);
    }
#pragma unroll
    for (int Nt = 0; Nt < 4; ++Nt) {
      const unsigned lo = pk2bf(fmaxf(acc[Nt][0],0.f), fmaxf(acc[Nt][1],0.f));
      const unsigned hi = pk2bf(fmaxf(acc[Nt][2],0.f), fmaxf(acc[Nt][3],0.f));
      uint2* dst = (uint2*)&h2[(Nt*16 + l15)*136 + Mt*16 + quad*4];
      *dst = make_uint2(lo, hi);
    }
  }
  __syncthreads();
  // ---- L3: 64x256x128 + fused relu/maxpool (no masking) ----
  bf16x8 a2[4][4];
#pragma unroll
  for (int mt = 0; mt < 4; ++mt)
#pragma unroll
    for (int kt = 0; kt < 4; ++kt)
      a2[mt][kt] = *(const bf16x8*)&h2[(mt*16 + l15)*136 + kt*32 + quad*8];
  const bf16x8* BW3 = (const bf16x8*)(ws + OFF_BW3);
  float vpv[8];
#pragma unroll
  for (int nt8 = 0; nt8 < 8; ++nt8) {
    const int nt = nhalf*8 + nt8;
    const int n = nt*16 + l15;
    const float bias = ws[OFF_B3 + n];
    f32x4 acc[4];
#pragma unroll
    for (int mt = 0; mt < 4; ++mt) acc[mt] = (f32x4){bias, bias, bias, bias};
#pragma unroll
    for (int kt = 0; kt < 4; ++kt) {
      const bf16x8 b = BW3[(nt*4+kt)*64 + lane];
#pragma unroll
      for (int mt = 0; mt < 4; ++mt)
        acc[mt] = __builtin_amdgcn_mfma_f32_16x16x32_bf16(a2[mt][kt], b, acc[mt], 0, 0, 0);
    }
    float mx = 0.f;   // relu >= 0 so 0 is a safe identity
#pragma unroll
    for (int mt = 0; mt < 4; ++mt) {
      mx = fmaxf(mx, fmaxf(fmaxf(acc[mt][0], acc[mt][1]), fmaxf(acc[mt][2], acc[mt][3])));
    }
    mx = fmaxf(mx, 0.f);
    mx = fmaxf(mx, __shfl_xor(mx, 16, 64));
    mx = fmaxf(mx, __shfl_xor(mx, 32, 64));
    vpv[nt8] = mx;
  }
  if (quad == 0) {
    float* vp = ws + OFF_VP + g*256 + nhalf*128;
#pragma unroll
    for (int nt8 = 0; nt8 < 8; ++nt8) vp[nt8*16 + l15] = vpv[nt8];
  }
}

// ---------------- kernel 3: heads via bf16 MFMA, fused transpose write ----------------
#define YSTRIDE 264
__global__ __launch_bounds__(256) void heads_kernel(float* __restrict__ ws, void* __restrict__ outv){
  const int isf32 = ((const volatile int*)(ws + OFF_FLAG))[0];
  __shared__ unsigned short y[16*YSTRIDE];
  const int t = threadIdx.x;
  const int wave = t >> 6, lane = t & 63;
  const int quad = lane >> 4, l15 = lane & 15;
  const int r0 = blockIdx.x * 16;
  bf16x8 a[8];
  const float* vp = ws + OFF_VP + (r0 + l15)*256;
#pragma unroll
  for (int kt = 0; kt < 8; ++kt) {
    const float4* v4 = (const float4*)(vp + kt*32 + quad*8);
    float4 u0 = v4[0], u1 = v4[1];
    a[kt][0]=(short)f2bf(u0.x); a[kt][1]=(short)f2bf(u0.y); a[kt][2]=(short)f2bf(u0.z); a[kt][3]=(short)f2bf(u0.w);
    a[kt][4]=(short)f2bf(u1.x); a[kt][5]=(short)f2bf(u1.y); a[kt][6]=(short)f2bf(u1.z); a[kt][7]=(short)f2bf(u1.w);
  }
  const bf16x8* HB1 = (const bf16x8*)(ws + OFF_HB1);
#pragma unroll
  for (int nt4 = 0; nt4 < 4; ++nt4) {
    const int nt = wave*4 + nt4;
    const int n = nt*16 + l15;
    const float bias = ws[OFF_HB1B + n];
    f32x4 acc = (f32x4){bias, bias, bias, bias};
#pragma unroll
    for (int kt = 0; kt < 8; ++kt)
      acc = __builtin_amdgcn_mfma_f32_16x16x32_bf16(a[kt], HB1[(nt*8+kt)*64 + lane], acc, 0, 0, 0);
#pragma unroll
    for (int jj = 0; jj < 4; ++jj)
      y[(quad*4+jj)*YSTRIDE + n] = f2bf(fmaxf(acc[jj], 0.f));
  }
  __syncthreads();
#pragma unroll
  for (int kt = 0; kt < 8; ++kt)
    a[kt] = *(const bf16x8*)&y[l15*YSTRIDE + kt*32 + quad*8];
  __syncthreads();
  const bf16x8* HB2 = (const bf16x8*)(ws + OFF_HB2);
#pragma unroll
  for (int nt4 = 0; nt4 < 4; ++nt4) {
    const int nt = wave*4 + nt4;
    const int n = nt*16 + l15;
    const float bias = ws[OFF_HB2B + n];
    f32x4 acc = (f32x4){bias, bias, bias, bias};
#pragma unroll
    for (int kt = 0; kt < 8; ++kt)
      acc = __builtin_amdgcn_mfma_f32_16x16x32_bf16(a[kt], HB2[(nt*8+kt)*64 + lane], acc, 0, 0, 0);
#pragma unroll
    for (int jj = 0; jj < 4; ++jj)
      y[(quad*4+jj)*YSTRIDE + n] = f2bf(fmaxf(acc[jj], 0.f));
  }
  __syncthreads();
#pragma unroll
  for (int kt = 0; kt < 8; ++kt)
    a[kt] = *(const bf16x8*)&y[l15*YSTRIDE + kt*32 + quad*8];
  const bf16x8* HB3 = (const bf16x8*)(ws + OFF_HB3);
  {
    const int n = wave*16 + l15;
    const float bias = ws[OFF_HB3B + n];
    f32x4 acc = (f32x4){bias, bias, bias, bias};
#pragma unroll
    for (int kt = 0; kt < 8; ++kt)
      acc = __builtin_amdgcn_mfma_f32_16x16x32_bf16(a[kt], HB3[(wave*8+kt)*64 + lane], acc, 0, 0, 0);
    if (n < 48) {
#pragma unroll
      for (int jj = 0; jj < 4; ++jj) {
        const int gr = r0 + quad*4 + jj;
        const int b = gr >> 12, rem = gr & 4095, s = rem >> 2, d = rem & 3;
        const int o = ((b*48 + n)*1024 + s)*4 + d;
        if (isf32) ((float*)outv)[o] = acc[jj];
        else       ((__hip_bfloat16*)outv)[o] = __float2bfloat16(acc[jj]);
      }
    }
  }
}

extern "C" void kernel_launch(void* const* d_in, const int* in_sizes, int n_in,
                              void* d_out, int out_size, void* d_ws, size_t ws_size,
                              hipStream_t stream) {
  float* ws = (float*)d_ws;
  Ptrs P;
  for (int i = 0; i < 25; ++i) P.p[i] = d_in[i];
  prep_kernel<<<(PREP_TOTAL+255)/256, 256, 0, stream>>>(P, ws);
  group_kernel<<<NB*NS/2, 256, 0, stream>>>(ws);
  mlp_kernel<<<NGROUP/2, 256, 0, stream>>>(ws);
  heads_kernel<<<NGROUP/16, 256, 0, stream>>>(ws, d_out);
}